// Round 9
// baseline (302.736 us; speedup 1.0000x reference)
//
#include <hip/hip_runtime.h>

namespace {

constexpr int B = 4, S = 4096, H = 16, D = 32;
constexpr int L = 32;             // chunk length
constexpr int NC = S / L;         // 128 chunks per sequence
constexpr int NBH = B * H;        // 64
constexpr int RS = H * D;         // 512 floats between consecutive time steps
constexpr int PW = 36;            // padded LDS row width (16B-aligned rows, conflict-free)
constexpr float GEPS = 1.52587890625e-05f;  // 2^-16 per-step decay clamp
                                            // (max 7 steps to sub-block end * 16 = 112 < 126)

// gfx950 hipcc launch-bounds lore (measured rounds 6-8):
//   __launch_bounds__(256, w) caps VGPR at ~256/w.
//   w=7 -> 36 regs -> 1.1 GB spill;  w=6 -> 40 regs -> spill;
//   unbounded -> 108 regs -> occupancy 18%.  w=4 -> 64 regs: the sweet spot
//   (k3's true working set is ~48 regs per rounds 3-4).

__device__ __forceinline__ float flog2(float x) { return __builtin_amdgcn_logf(x); }
__device__ __forceinline__ float fexp2(float x) { return __builtin_amdgcn_exp2f(x); }

// ---------------- Kernel 1: per-chunk summaries ----------------
// l = cumsum log2(max(g,GEPS)); W_j[m] = v_j[m]*2^{l_end[m]-l_j[m]} (<=1)
// KVb[bh][c][d][m] = sum_j k_j[d]*W_j[m];  Gb[bh][c][m] = 2^{l_end[m]}
// Scan: column-parallel in LDS (3 barriers, no shuffles -> low VGPR).
__global__ __launch_bounds__(256)
void k1_chunk_summary(const float* __restrict__ Kp, const float* __restrict__ Vp,
                      const float* __restrict__ Gp, float* __restrict__ KVb,
                      float* __restrict__ Gb)
{
    __shared__ float k_s[L][PW];
    __shared__ float w_s[L][PW];   // v at load; scaled to W in place
    __shared__ float lg[L][PW];    // per-row log2(gate)
    __shared__ float sub[8][D];    // 4-row group subtotals

    const int blk = blockIdx.x;
    const int bh = blk / NC, c = blk % NC;
    const int b = bh / H, h = bh % H;
    const long base = ((long)b * S + (long)c * L) * RS + h * D;

    const int tid = threadIdx.x;
    const int i = tid >> 3;          // row 0..31
    const int u = (tid & 7) * 4;     // col quad
    const long roff = base + (long)i * RS + u;

    float4 k4 = *(const float4*)(Kp + roff);
    float4 v4 = *(const float4*)(Vp + roff);
    float4 g4 = *(const float4*)(Gp + roff);
    *(float4*)&k_s[i][u] = k4;
    *(float4*)&w_s[i][u] = v4;
    float4 lv;
    lv.x = flog2(fmaxf(g4.x, GEPS));
    lv.y = flog2(fmaxf(g4.y, GEPS));
    lv.z = flog2(fmaxf(g4.z, GEPS));
    lv.w = flog2(fmaxf(g4.w, GEPS));
    *(float4*)&lg[i][u] = lv;
    __syncthreads();                               // b1

    // column scan: thread -> (column m, 4-row group t)
    const int m = tid & 31, t = tid >> 5;
    const int r0 = t * 4;
    float c0 = lg[r0 + 0][m];
    float c1 = c0 + lg[r0 + 1][m];
    float c2 = c1 + lg[r0 + 2][m];
    float c3 = c2 + lg[r0 + 3][m];
    sub[t][m] = c3;
    __syncthreads();                               // b2

    float sb[8];
    float total = 0.f;
    #pragma unroll
    for (int tt = 0; tt < 8; ++tt) { sb[tt] = sub[tt][m]; total += sb[tt]; }
    float base_l = 0.f;
    #pragma unroll
    for (int tt = 0; tt < 8; ++tt) { if (tt < t) base_l += sb[tt]; }
    // W = v * 2^{total - l}   (exponent <= 0)
    w_s[r0 + 0][m] *= fexp2(total - (base_l + c0));
    w_s[r0 + 1][m] *= fexp2(total - (base_l + c1));
    w_s[r0 + 2][m] *= fexp2(total - (base_l + c2));
    w_s[r0 + 3][m] *= fexp2(total - (base_l + c3));
    if (t == 0) Gb[(long)(bh * NC + c) * D + m] = fexp2(total);
    __syncthreads();                               // b3

    // KV[d][m] = sum_j k[j][d] * W[j][m]
    const int d = tid >> 3;
    const int mg = (tid & 7) * 4;
    float4 acc = {0, 0, 0, 0};
    #pragma unroll
    for (int j = 0; j < L; ++j) {
        float kv = k_s[j][d];
        float4 w = *(float4*)&w_s[j][mg];
        acc.x += kv * w.x; acc.y += kv * w.y; acc.z += kv * w.z; acc.w += kv * w.w;
    }
    *(float4*)(KVb + (long)(bh * NC + c) * (D * D) + d * D + mg) = acc;
}

// ---------------- Kernel 2: inter-chunk scan (in-place KV -> S0) ----------------
// 8-deep batched prefetch; all register indices static.
__global__ __launch_bounds__(256)
void k2_scan(float* __restrict__ KVb, const float* __restrict__ Gb)
{
    const int bh = blockIdx.x >> 2;
    const int dg = blockIdx.x & 3;
    const int tid = threadIdx.x;
    const int d = dg * 8 + (tid >> 5);
    const int m = tid & 31;

    const long kvoff = (long)bh * NC * (D * D) + d * D + m;
    const long goff = (long)bh * NC * D + m;

    float ka[8], ga[8];
    #pragma unroll
    for (int t = 0; t < 8; ++t) {
        ka[t] = KVb[kvoff + (long)t * (D * D)];
        ga[t] = Gb[goff + (long)t * D];
    }
    float st = 0.f;
    for (int c0 = 0; c0 < NC; c0 += 8) {
        float kb[8], gb2[8];
        const bool more = (c0 + 8) < NC;
        #pragma unroll
        for (int t = 0; t < 8; ++t) {
            kb[t]  = more ? KVb[kvoff + (long)(c0 + 8 + t) * (D * D)] : 0.f;
            gb2[t] = more ? Gb[goff + (long)(c0 + 8 + t) * D] : 0.f;
        }
        #pragma unroll
        for (int t = 0; t < 8; ++t) {
            KVb[kvoff + (long)(c0 + t) * (D * D)] = st;   // chunk-START state
            st = ga[t] * st + ka[t];
        }
        #pragma unroll
        for (int t = 0; t < 8; ++t) { ka[t] = kb[t]; ga[t] = gb2[t]; }
    }
}

// ---------------- Kernel 3: per-chunk outputs ----------------
// out_i[m] = 2^{l_i[m]}*(q_i.S0[:,m])
//          + sum_{s<=si} 2^{l_i[m]-e_s[m]} * sum_{j in s, j<=i} A_ij*W_j[m]
// W_j[m] = v_j[m]*2^{e_{s(j)}[m]-l_j[m]};  e_s = l at row 8s+7 (sub-block end).
// 3 barriers. S0: one float4/thread global read at start, staged into the
// kT LDS slot after the A-matmul no longer needs it (union overlay).
__global__ __launch_bounds__(256, 4)   // VGPR cap ~64; working set is ~48 (r3/r4)
void k3_out(const float* __restrict__ Qp, const float* __restrict__ Kp,
            const float* __restrict__ Vp, const float* __restrict__ Gp,
            const float* __restrict__ S0b, float* __restrict__ Op)
{
    __shared__ float q_s[L][PW];
    __shared__ union KtS0 {               // kT dead after barrier b2 -> reuse for S0
        float kT[D][L + 1];
        float s0[D][PW];
    } kts;
    __shared__ float w_s[L][PW];   // v at load; scaled to W in place
    __shared__ float l_s[L][PW];   // logs at load; overwritten with final l
    __shared__ float a_s[L][L + 1];
    __shared__ float sub[8][D];

    const int blk = blockIdx.x;
    const int bh = blk / NC, c = blk % NC;
    const int b = bh / H, h = bh % H;
    const long base = ((long)b * S + (long)c * L) * RS + h * D;

    const int tid = threadIdx.x;
    const int i = tid >> 3;
    const int u = (tid & 7) * 4;
    const int wv = i >> 3;           // sub-block id (wave-uniform)
    const long roff = base + (long)i * RS + u;

    float4 q4 = *(const float4*)(Qp + roff);
    float4 k4 = *(const float4*)(Kp + roff);
    float4 v4 = *(const float4*)(Vp + roff);
    float4 g4 = *(const float4*)(Gp + roff);
    float4 s04 = *(const float4*)(S0b + (long)(bh * NC + c) * (D * D) + tid * 4);

    *(float4*)&q_s[i][u] = q4;
    kts.kT[u + 0][i] = k4.x; kts.kT[u + 1][i] = k4.y;
    kts.kT[u + 2][i] = k4.z; kts.kT[u + 3][i] = k4.w;
    *(float4*)&w_s[i][u] = v4;
    float4 lv;
    lv.x = flog2(fmaxf(g4.x, GEPS));
    lv.y = flog2(fmaxf(g4.y, GEPS));
    lv.z = flog2(fmaxf(g4.z, GEPS));
    lv.w = flog2(fmaxf(g4.w, GEPS));
    *(float4*)&l_s[i][u] = lv;
    __syncthreads();                               // b1

    // --- phase A: column subtotals + A-matmul (independent work) ---
    const int m = tid & 31, t = tid >> 5;
    const int r0 = t * 4;
    float c0 = l_s[r0 + 0][m];
    float c1 = c0 + l_s[r0 + 1][m];
    float c2 = c1 + l_s[r0 + 2][m];
    float c3 = c2 + l_s[r0 + 3][m];
    sub[t][m] = c3;

    // A[i][u..u+3] = q_i . k_j (unmasked; consumers use j<=i only)
    {
        float4 a = {0, 0, 0, 0};
        #pragma unroll
        for (int dd = 0; dd < 8; ++dd) {
            float4 qd = *(float4*)&q_s[i][dd * 4];
            #pragma unroll
            for (int cc = 0; cc < 4; ++cc) {
                const float qv = (&qd.x)[cc];
                const int d = dd * 4 + cc;
                a.x += qv * kts.kT[d][u + 0];
                a.y += qv * kts.kT[d][u + 1];
                a.z += qv * kts.kT[d][u + 2];
                a.w += qv * kts.kT[d][u + 3];
            }
        }
        a_s[i][u + 0] = a.x; a_s[i][u + 1] = a.y;
        a_s[i][u + 2] = a.z; a_s[i][u + 3] = a.w;
    }
    __syncthreads();                               // b2  (kT dead from here)

    // --- phase B: finalize l (in place), scale W (in place), stage S0 ---
    {
        float sb[8];
        #pragma unroll
        for (int tt = 0; tt < 8; ++tt) sb[tt] = sub[tt][m];
        float base_l = 0.f;
        #pragma unroll
        for (int tt = 0; tt < 8; ++tt) { if (tt < t) base_l += sb[tt]; }
        float es_own = 0.f;          // l at end of this group's sub-block (row (t|1)*4+3)
        const int tcap = t | 1;
        #pragma unroll
        for (int tt = 0; tt < 8; ++tt) { if (tt <= tcap) es_own += sb[tt]; }
        const float l0 = base_l + c0, l1 = base_l + c1,
                    l2 = base_l + c2, l3 = base_l + c3;
        l_s[r0 + 0][m] = l0; l_s[r0 + 1][m] = l1;
        l_s[r0 + 2][m] = l2; l_s[r0 + 3][m] = l3;
        // W = v * 2^{e_s - l}  (exponent <= 0)
        w_s[r0 + 0][m] *= fexp2(es_own - l0);
        w_s[r0 + 1][m] *= fexp2(es_own - l1);
        w_s[r0 + 2][m] *= fexp2(es_own - l2);
        w_s[r0 + 3][m] *= fexp2(es_own - l3);
    }
    *(float4*)&kts.s0[tid >> 3][(tid & 7) * 4] = s04;   // stage S0 into old kT slot
    __syncthreads();                               // b3

    // --- phase C: outputs ---
    const float4 val = *(float4*)&l_s[i][u];       // final l_i

    // cross-chunk: 2^{l_i} * (q_i . S0[:,m])
    float4 o = {0, 0, 0, 0};
    #pragma unroll
    for (int dd = 0; dd < 8; ++dd) {
        float4 qd = *(float4*)&q_s[i][dd * 4];
        #pragma unroll
        for (int cc = 0; cc < 4; ++cc) {
            const float qv = (&qd.x)[cc];
            float4 s4 = *(float4*)&kts.s0[dd * 4 + cc][u];
            o.x += qv * s4.x; o.y += qv * s4.y; o.z += qv * s4.z; o.w += qv * s4.w;
        }
    }
    o.x *= fexp2(val.x); o.y *= fexp2(val.y);
    o.z *= fexp2(val.z); o.w *= fexp2(val.w);

    // intra-chunk, sub-block factorized; e_s read from l_s rows 8s+7
    #pragma unroll
    for (int s2 = 0; s2 < 4; ++s2) {
        if (s2 <= wv) {
            float4 tc = {0, 0, 0, 0};
            if (s2 < wv) {
                #pragma unroll
                for (int jj = 0; jj < 8; ++jj) {
                    const float av = a_s[i][s2 * 8 + jj];
                    float4 w = *(float4*)&w_s[s2 * 8 + jj][u];
                    tc.x += av * w.x; tc.y += av * w.y;
                    tc.z += av * w.z; tc.w += av * w.w;
                }
            } else {
                #pragma unroll
                for (int jj = 0; jj < 8; ++jj) {
                    const int j = s2 * 8 + jj;
                    const float av = (j <= i) ? a_s[i][j] : 0.f;
                    float4 w = *(float4*)&w_s[j][u];
                    tc.x += av * w.x; tc.y += av * w.y;
                    tc.z += av * w.z; tc.w += av * w.w;
                }
            }
            float4 e4 = *(float4*)&l_s[s2 * 8 + 7][u];
            // s2<wv: exponent <= 0; s2==wv: in [0,112] -> finite
            o.x += fexp2(val.x - e4.x) * tc.x;
            o.y += fexp2(val.y - e4.y) * tc.y;
            o.z += fexp2(val.z - e4.z) * tc.z;
            o.w += fexp2(val.w - e4.w) * tc.w;
        }
    }

    *(float4*)(Op + roff) = o;
}

} // namespace

extern "C" void kernel_launch(void* const* d_in, const int* in_sizes, int n_in,
                              void* d_out, int out_size, void* d_ws, size_t ws_size,
                              hipStream_t stream)
{
    const float* q = (const float*)d_in[0];
    const float* k = (const float*)d_in[1];
    const float* v = (const float*)d_in[2];
    const float* g = (const float*)d_in[3];
    float* out = (float*)d_out;

    float* KVb = (float*)d_ws;                       // [NBH][NC][D][D]  (33.55 MB)
    float* Gb = KVb + (long)NBH * NC * D * D;        // [NBH][NC][D]     (1.05 MB)

    dim3 blk(256);
    k1_chunk_summary<<<dim3(NBH * NC), blk, 0, stream>>>(k, v, g, KVb, Gb);
    k2_scan<<<dim3(NBH * 4), blk, 0, stream>>>(KVb, Gb);
    k3_out<<<dim3(NBH * NC), blk, 0, stream>>>(q, k, v, g, KVb, out);
}

// Round 10
// 94.770 us; speedup vs baseline: 3.1944x; 3.1944x over previous
//
#include <hip/hip_runtime.h>

namespace {

constexpr int B = 4, S = 4096, H = 16, D = 32;
constexpr int L = 32;             // chunk length
constexpr int NC = S / L;         // 128 chunks per sequence
constexpr int NBH = B * H;        // 64
constexpr int RS = H * D;         // 512 floats between consecutive time steps
constexpr int PW = 36;            // padded LDS row width (16B-aligned rows, conflict-free)
constexpr float GEPS = 1.52587890625e-05f;  // 2^-16 per-step decay clamp
                                            // (max 7 steps to sub-block end * 16 = 112 < 126)

// gfx950 hipcc register lore (rounds 6-9, measured):
//   __launch_bounds__(256, w) caps VGPR at ~256/w; capping below the
//   compiler's chosen live set causes scratch spill (~0.7-1.1 GB traffic).
//   The live set itself is set by unrolling: a fully-unrolled phase with
//   many LDS reads and no barriers hoists everything -> 108 regs.
//   Fix DEMAND (runtime-bounded loops), not the cap.

__device__ __forceinline__ float flog2(float x) { return __builtin_amdgcn_logf(x); }
__device__ __forceinline__ float fexp2(float x) { return __builtin_amdgcn_exp2f(x); }

// ---------------- Kernel 1: per-chunk summaries ----------------
// l = cumsum log2(max(g,GEPS)); W_j[m] = v_j[m]*2^{l_end[m]-l_j[m]} (<=1)
// KVb[bh][c][d][m] = sum_j k_j[d]*W_j[m];  Gb[bh][c][m] = 2^{l_end[m]}
__global__ __launch_bounds__(256)
void k1_chunk_summary(const float* __restrict__ Kp, const float* __restrict__ Vp,
                      const float* __restrict__ Gp, float* __restrict__ KVb,
                      float* __restrict__ Gb)
{
    __shared__ float k_s[L][PW];
    __shared__ float w_s[L][PW];   // v at load; scaled to W in place
    __shared__ float lg[L][PW];    // per-row log2(gate)
    __shared__ float sub[8][D];    // 4-row group subtotals

    const int blk = blockIdx.x;
    const int bh = blk / NC, c = blk % NC;
    const int b = bh / H, h = bh % H;
    const long base = ((long)b * S + (long)c * L) * RS + h * D;

    const int tid = threadIdx.x;
    const int i = tid >> 3;          // row 0..31
    const int u = (tid & 7) * 4;     // col quad
    const long roff = base + (long)i * RS + u;

    float4 k4 = *(const float4*)(Kp + roff);
    float4 v4 = *(const float4*)(Vp + roff);
    float4 g4 = *(const float4*)(Gp + roff);
    *(float4*)&k_s[i][u] = k4;
    *(float4*)&w_s[i][u] = v4;
    float4 lv;
    lv.x = flog2(fmaxf(g4.x, GEPS));
    lv.y = flog2(fmaxf(g4.y, GEPS));
    lv.z = flog2(fmaxf(g4.z, GEPS));
    lv.w = flog2(fmaxf(g4.w, GEPS));
    *(float4*)&lg[i][u] = lv;
    __syncthreads();                               // b1

    // column scan: thread -> (column m, 4-row group t)
    const int m = tid & 31, t = tid >> 5;
    const int r0 = t * 4;
    float c0 = lg[r0 + 0][m];
    float c1 = c0 + lg[r0 + 1][m];
    float c2 = c1 + lg[r0 + 2][m];
    float c3 = c2 + lg[r0 + 3][m];
    sub[t][m] = c3;
    __syncthreads();                               // b2

    float sb[8];
    float total = 0.f;
    #pragma unroll
    for (int tt = 0; tt < 8; ++tt) { sb[tt] = sub[tt][m]; total += sb[tt]; }
    float base_l = 0.f;
    #pragma unroll
    for (int tt = 0; tt < 8; ++tt) { if (tt < t) base_l += sb[tt]; }
    // W = v * 2^{total - l}   (exponent <= 0)
    w_s[r0 + 0][m] *= fexp2(total - (base_l + c0));
    w_s[r0 + 1][m] *= fexp2(total - (base_l + c1));
    w_s[r0 + 2][m] *= fexp2(total - (base_l + c2));
    w_s[r0 + 3][m] *= fexp2(total - (base_l + c3));
    if (t == 0) Gb[(long)(bh * NC + c) * D + m] = fexp2(total);
    __syncthreads();                               // b3

    // KV[d][m] = sum_j k[j][d] * W[j][m]
    const int d = tid >> 3;
    const int mg = (tid & 7) * 4;
    float4 acc = {0, 0, 0, 0};
    #pragma unroll
    for (int j = 0; j < L; ++j) {
        float kv = k_s[j][d];
        float4 w = *(float4*)&w_s[j][mg];
        acc.x += kv * w.x; acc.y += kv * w.y; acc.z += kv * w.z; acc.w += kv * w.w;
    }
    *(float4*)(KVb + (long)(bh * NC + c) * (D * D) + d * D + mg) = acc;
}

// ---------------- Kernel 2: inter-chunk scan (in-place KV -> S0) ----------------
__global__ __launch_bounds__(256)
void k2_scan(float* __restrict__ KVb, const float* __restrict__ Gb)
{
    const int bh = blockIdx.x >> 2;
    const int dg = blockIdx.x & 3;
    const int tid = threadIdx.x;
    const int d = dg * 8 + (tid >> 5);
    const int m = tid & 31;

    const long kvoff = (long)bh * NC * (D * D) + d * D + m;
    const long goff = (long)bh * NC * D + m;

    float ka[8], ga[8];
    #pragma unroll
    for (int t = 0; t < 8; ++t) {
        ka[t] = KVb[kvoff + (long)t * (D * D)];
        ga[t] = Gb[goff + (long)t * D];
    }
    float st = 0.f;
    for (int c0 = 0; c0 < NC; c0 += 8) {
        float kb[8], gb2[8];
        const bool more = (c0 + 8) < NC;
        #pragma unroll
        for (int t = 0; t < 8; ++t) {
            kb[t]  = more ? KVb[kvoff + (long)(c0 + 8 + t) * (D * D)] : 0.f;
            gb2[t] = more ? Gb[goff + (long)(c0 + 8 + t) * D] : 0.f;
        }
        #pragma unroll
        for (int t = 0; t < 8; ++t) {
            KVb[kvoff + (long)(c0 + t) * (D * D)] = st;   // chunk-START state
            st = ga[t] * st + ka[t];
        }
        #pragma unroll
        for (int t = 0; t < 8; ++t) { ka[t] = kb[t]; ga[t] = gb2[t]; }
    }
}

// ---------------- Kernel 3: per-chunk outputs ----------------
// out_i[m] = 2^{l_i[m]}*(q_i.S0[:,m])
//          + sum_{s<=si} 2^{l_i[m]-e_s[m]} * sum_{j in s, j<=i} A_ij*W_j[m]
// W_j[m] = v_j[m]*2^{e_{s(j)}[m]-l_j[m]};  e_s = l at row 8s+7.
// 3 barriers; phase-C intra loop RUNTIME-bounded (s<=wv, wave-uniform) to
// keep register demand at round-4 levels (~48) -- see lore at top.
__global__ __launch_bounds__(256)
void k3_out(const float* __restrict__ Qp, const float* __restrict__ Kp,
            const float* __restrict__ Vp, const float* __restrict__ Gp,
            const float* __restrict__ S0b, float* __restrict__ Op)
{
    __shared__ float q_s[L][PW];
    __shared__ union KtS0 {               // kT dead after barrier b2 -> reuse for S0
        float kT[D][L + 1];
        float s0[D][PW];
    } kts;
    __shared__ float w_s[L][PW];   // v at load; scaled to W in place
    __shared__ float l_s[L][PW];   // logs at load; overwritten with final l
    __shared__ float a_s[L][L + 1];
    __shared__ float sub[8][D];

    const int blk = blockIdx.x;
    const int bh = blk / NC, c = blk % NC;
    const int b = bh / H, h = bh % H;
    const long base = ((long)b * S + (long)c * L) * RS + h * D;

    const int tid = threadIdx.x;
    const int i = tid >> 3;
    const int u = (tid & 7) * 4;
    const int wv = i >> 3;           // sub-block id (wave-uniform)
    const long roff = base + (long)i * RS + u;

    float4 q4 = *(const float4*)(Qp + roff);
    float4 k4 = *(const float4*)(Kp + roff);
    float4 v4 = *(const float4*)(Vp + roff);
    float4 g4 = *(const float4*)(Gp + roff);
    float4 s04 = *(const float4*)(S0b + (long)(bh * NC + c) * (D * D) + tid * 4);

    *(float4*)&q_s[i][u] = q4;
    kts.kT[u + 0][i] = k4.x; kts.kT[u + 1][i] = k4.y;
    kts.kT[u + 2][i] = k4.z; kts.kT[u + 3][i] = k4.w;
    *(float4*)&w_s[i][u] = v4;
    float4 lv;
    lv.x = flog2(fmaxf(g4.x, GEPS));
    lv.y = flog2(fmaxf(g4.y, GEPS));
    lv.z = flog2(fmaxf(g4.z, GEPS));
    lv.w = flog2(fmaxf(g4.w, GEPS));
    *(float4*)&l_s[i][u] = lv;
    __syncthreads();                               // b1

    // --- phase A: column subtotals + A-matmul ---
    const int m = tid & 31, t = tid >> 5;
    const int r0 = t * 4;
    float c0 = l_s[r0 + 0][m];
    float c1 = c0 + l_s[r0 + 1][m];
    float c2 = c1 + l_s[r0 + 2][m];
    float c3 = c2 + l_s[r0 + 3][m];
    sub[t][m] = c3;

    // A[i][u..u+3] = q_i . k_j (unmasked; consumers use j<=i only)
    {
        float4 a = {0, 0, 0, 0};
        #pragma unroll
        for (int dd = 0; dd < 8; ++dd) {
            float4 qd = *(float4*)&q_s[i][dd * 4];
            #pragma unroll
            for (int cc = 0; cc < 4; ++cc) {
                const float qv = (&qd.x)[cc];
                const int d = dd * 4 + cc;
                a.x += qv * kts.kT[d][u + 0];
                a.y += qv * kts.kT[d][u + 1];
                a.z += qv * kts.kT[d][u + 2];
                a.w += qv * kts.kT[d][u + 3];
            }
        }
        a_s[i][u + 0] = a.x; a_s[i][u + 1] = a.y;
        a_s[i][u + 2] = a.z; a_s[i][u + 3] = a.w;
    }
    __syncthreads();                               // b2  (kT dead from here)

    // --- phase B: finalize l (in place), scale W (in place), stage S0 ---
    {
        float sb[8];
        #pragma unroll
        for (int tt = 0; tt < 8; ++tt) sb[tt] = sub[tt][m];
        float base_l = 0.f;
        #pragma unroll
        for (int tt = 0; tt < 8; ++tt) { if (tt < t) base_l += sb[tt]; }
        float es_own = 0.f;          // l at end of this group's sub-block
        const int tcap = t | 1;
        #pragma unroll
        for (int tt = 0; tt < 8; ++tt) { if (tt <= tcap) es_own += sb[tt]; }
        const float l0 = base_l + c0, l1 = base_l + c1,
                    l2 = base_l + c2, l3 = base_l + c3;
        l_s[r0 + 0][m] = l0; l_s[r0 + 1][m] = l1;
        l_s[r0 + 2][m] = l2; l_s[r0 + 3][m] = l3;
        // W = v * 2^{e_s - l}  (exponent <= 0)
        w_s[r0 + 0][m] *= fexp2(es_own - l0);
        w_s[r0 + 1][m] *= fexp2(es_own - l1);
        w_s[r0 + 2][m] *= fexp2(es_own - l2);
        w_s[r0 + 3][m] *= fexp2(es_own - l3);
    }
    *(float4*)&kts.s0[tid >> 3][(tid & 7) * 4] = s04;   // stage S0 into old kT slot
    __syncthreads();                               // b3

    // --- phase C: outputs ---
    const float4 val = *(float4*)&l_s[i][u];       // final l_i

    // cross-chunk: 2^{l_i} * (q_i . S0[:,m])
    float4 o = {0, 0, 0, 0};
    #pragma unroll
    for (int dd = 0; dd < 8; ++dd) {
        float4 qd = *(float4*)&q_s[i][dd * 4];
        #pragma unroll
        for (int cc = 0; cc < 4; ++cc) {
            const float qv = (&qd.x)[cc];
            float4 s4 = *(float4*)&kts.s0[dd * 4 + cc][u];
            o.x += qv * s4.x; o.y += qv * s4.y; o.z += qv * s4.z; o.w += qv * s4.w;
        }
    }
    o.x *= fexp2(val.x); o.y *= fexp2(val.y);
    o.z *= fexp2(val.z); o.w *= fexp2(val.w);

    // intra-chunk, sub-block factorized; RUNTIME loop bound (wave-uniform)
    for (int s = 0; s <= wv; ++s) {
        float4 tc = {0, 0, 0, 0};
        const int jb = s << 3;
        if (s < wv) {
            #pragma unroll
            for (int jj = 0; jj < 8; ++jj) {
                const float av = a_s[i][jb + jj];
                float4 w = *(float4*)&w_s[jb + jj][u];
                tc.x += av * w.x; tc.y += av * w.y;
                tc.z += av * w.z; tc.w += av * w.w;
            }
        } else {
            #pragma unroll
            for (int jj = 0; jj < 8; ++jj) {
                const int j = jb + jj;
                const float av = (j <= i) ? a_s[i][j] : 0.f;
                float4 w = *(float4*)&w_s[j][u];
                tc.x += av * w.x; tc.y += av * w.y;
                tc.z += av * w.z; tc.w += av * w.w;
            }
        }
        float4 e4 = *(float4*)&l_s[jb + 7][u];
        // s<wv: exponent <= 0; s==wv: in [0,112] -> finite
        o.x += fexp2(val.x - e4.x) * tc.x;
        o.y += fexp2(val.y - e4.y) * tc.y;
        o.z += fexp2(val.z - e4.z) * tc.z;
        o.w += fexp2(val.w - e4.w) * tc.w;
    }

    *(float4*)(Op + roff) = o;
}

} // namespace

extern "C" void kernel_launch(void* const* d_in, const int* in_sizes, int n_in,
                              void* d_out, int out_size, void* d_ws, size_t ws_size,
                              hipStream_t stream)
{
    const float* q = (const float*)d_in[0];
    const float* k = (const float*)d_in[1];
    const float* v = (const float*)d_in[2];
    const float* g = (const float*)d_in[3];
    float* out = (float*)d_out;

    float* KVb = (float*)d_ws;                       // [NBH][NC][D][D]  (33.55 MB)
    float* Gb = KVb + (long)NBH * NC * D * D;        // [NBH][NC][D]     (1.05 MB)

    dim3 blk(256);
    k1_chunk_summary<<<dim3(NBH * NC), blk, 0, stream>>>(k, v, g, KVb, Gb);
    k2_scan<<<dim3(NBH * 4), blk, 0, stream>>>(KVb, Gb);
    k3_out<<<dim3(NBH * NC), blk, 0, stream>>>(q, k, v, g, KVb, out);
}

// Round 11
// 92.544 us; speedup vs baseline: 3.2713x; 1.0241x over previous
//
#include <hip/hip_runtime.h>

namespace {

constexpr int B = 4, S = 4096, H = 16, D = 32;
constexpr int L = 32;             // chunk length
constexpr int NC = S / L;         // 128 chunks per sequence
constexpr int NBH = B * H;        // 64
constexpr int RS = H * D;         // 512 floats between consecutive time steps
constexpr int PW = 36;            // padded LDS row width (16B-aligned rows, conflict-free)
constexpr float GEPS = 1.52587890625e-05f;  // 2^-16 per-step decay clamp
                                            // (max 7 steps to sub-block end * 16 = 112 < 126)

// gfx950 hipcc register lore (rounds 6-10, measured):
//   - __launch_bounds__(256,w) caps VGPR at ~256/w; cap < live set => GB-scale
//     scratch spill. Never cap below demand.
//   - Demand is set by unrolling: fully-unrolled multi-LDS-read phases hoist
//     everything (108 regs); runtime-bounded wave-uniform loops keep ~40-70.
//   - tq[8] q-row preload (32 regs) is worth it: feeds A-matmul + S0-dot from
//     registers (r3-proposal: 53.5 us vs r10's 63 us without it).

__device__ __forceinline__ float flog2(float x) { return __builtin_amdgcn_logf(x); }
__device__ __forceinline__ float fexp2(float x) { return __builtin_amdgcn_exp2f(x); }

// ---------------- Kernel 1: per-chunk summaries ----------------
// l = cumsum log2(max(g,GEPS)); W_j[m] = v_j[m]*2^{l_end[m]-l_j[m]} (<=1)
// KVb[bh][c][d][m] = sum_j k_j[d]*W_j[m];  Gb[bh][c][m] = 2^{l_end[m]}
__global__ __launch_bounds__(256)
void k1_chunk_summary(const float* __restrict__ Kp, const float* __restrict__ Vp,
                      const float* __restrict__ Gp, float* __restrict__ KVb,
                      float* __restrict__ Gb)
{
    __shared__ float k_s[L][PW];
    __shared__ float w_s[L][PW];   // v at load; scaled to W in place
    __shared__ float lg[L][PW];    // per-row log2(gate)
    __shared__ float sub[8][D];    // 4-row group subtotals

    const int blk = blockIdx.x;
    const int bh = blk / NC, c = blk % NC;
    const int b = bh / H, h = bh % H;
    const long base = ((long)b * S + (long)c * L) * RS + h * D;

    const int tid = threadIdx.x;
    const int i = tid >> 3;          // row 0..31
    const int u = (tid & 7) * 4;     // col quad
    const long roff = base + (long)i * RS + u;

    float4 k4 = *(const float4*)(Kp + roff);
    float4 v4 = *(const float4*)(Vp + roff);
    float4 g4 = *(const float4*)(Gp + roff);
    *(float4*)&k_s[i][u] = k4;
    *(float4*)&w_s[i][u] = v4;
    float4 lv;
    lv.x = flog2(fmaxf(g4.x, GEPS));
    lv.y = flog2(fmaxf(g4.y, GEPS));
    lv.z = flog2(fmaxf(g4.z, GEPS));
    lv.w = flog2(fmaxf(g4.w, GEPS));
    *(float4*)&lg[i][u] = lv;
    __syncthreads();                               // b1

    // column scan: thread -> (column m, 4-row group t)
    const int m = tid & 31, t = tid >> 5;
    const int r0 = t * 4;
    float c0 = lg[r0 + 0][m];
    float c1 = c0 + lg[r0 + 1][m];
    float c2 = c1 + lg[r0 + 2][m];
    float c3 = c2 + lg[r0 + 3][m];
    sub[t][m] = c3;
    __syncthreads();                               // b2

    float sb[8];
    float total = 0.f;
    #pragma unroll
    for (int tt = 0; tt < 8; ++tt) { sb[tt] = sub[tt][m]; total += sb[tt]; }
    float base_l = 0.f;
    #pragma unroll
    for (int tt = 0; tt < 8; ++tt) { if (tt < t) base_l += sb[tt]; }
    // W = v * 2^{total - l}   (exponent <= 0)
    w_s[r0 + 0][m] *= fexp2(total - (base_l + c0));
    w_s[r0 + 1][m] *= fexp2(total - (base_l + c1));
    w_s[r0 + 2][m] *= fexp2(total - (base_l + c2));
    w_s[r0 + 3][m] *= fexp2(total - (base_l + c3));
    if (t == 0) Gb[(long)(bh * NC + c) * D + m] = fexp2(total);
    __syncthreads();                               // b3

    // KV[d][m] = sum_j k[j][d] * W[j][m]
    const int d = tid >> 3;
    const int mg = (tid & 7) * 4;
    float4 acc = {0, 0, 0, 0};
    #pragma unroll
    for (int j = 0; j < L; ++j) {
        float kv = k_s[j][d];
        float4 w = *(float4*)&w_s[j][mg];
        acc.x += kv * w.x; acc.y += kv * w.y; acc.z += kv * w.z; acc.w += kv * w.w;
    }
    *(float4*)(KVb + (long)(bh * NC + c) * (D * D) + d * D + mg) = acc;
}

// ---------------- Kernel 2: inter-chunk scan (in-place KV -> S0) ----------------
__global__ __launch_bounds__(256)
void k2_scan(float* __restrict__ KVb, const float* __restrict__ Gb)
{
    const int bh = blockIdx.x >> 2;
    const int dg = blockIdx.x & 3;
    const int tid = threadIdx.x;
    const int d = dg * 8 + (tid >> 5);
    const int m = tid & 31;

    const long kvoff = (long)bh * NC * (D * D) + d * D + m;
    const long goff = (long)bh * NC * D + m;

    float ka[8], ga[8];
    #pragma unroll
    for (int t = 0; t < 8; ++t) {
        ka[t] = KVb[kvoff + (long)t * (D * D)];
        ga[t] = Gb[goff + (long)t * D];
    }
    float st = 0.f;
    for (int c0 = 0; c0 < NC; c0 += 8) {
        float kb[8], gb2[8];
        const bool more = (c0 + 8) < NC;
        #pragma unroll
        for (int t = 0; t < 8; ++t) {
            kb[t]  = more ? KVb[kvoff + (long)(c0 + 8 + t) * (D * D)] : 0.f;
            gb2[t] = more ? Gb[goff + (long)(c0 + 8 + t) * D] : 0.f;
        }
        #pragma unroll
        for (int t = 0; t < 8; ++t) {
            KVb[kvoff + (long)(c0 + t) * (D * D)] = st;   // chunk-START state
            st = ga[t] * st + ka[t];
        }
        #pragma unroll
        for (int t = 0; t < 8; ++t) { ka[t] = kb[t]; ga[t] = gb2[t]; }
    }
}

// ---------------- Kernel 3: per-chunk outputs ----------------
// out_i[m] = 2^{l_i[m]}*(q_i.S0[:,m])
//          + sum_{s<=wv} 2^{l_i[m]-e_s[m]} * sum_{j in s, j<=i} A_ij*W_j[m]
// W_j[m] = v_j[m]*2^{e_{s(j)}[m]-l_j[m]};  e_s = l at row 8s+7.
// 3 barriers; runtime-bounded intra loop (keeps regs ~40-70); tq[8] q-row
// register preload feeds A-matmul and S0-dot (the r3-proposal ILP win).
__global__ __launch_bounds__(256)
void k3_out(const float* __restrict__ Qp, const float* __restrict__ Kp,
            const float* __restrict__ Vp, const float* __restrict__ Gp,
            const float* __restrict__ S0b, float* __restrict__ Op)
{
    __shared__ float q_s[L][PW];
    __shared__ union KtS0 {               // kT dead after barrier b2 -> reuse for S0
        float kT[D][L + 1];
        float s0[D][PW];
    } kts;
    __shared__ float w_s[L][PW];   // v at load; scaled to W in place
    __shared__ float l_s[L][PW];   // logs at load; overwritten with final l
    __shared__ float a_s[L][L + 1];
    __shared__ float sub[8][D];

    const int blk = blockIdx.x;
    const int bh = blk / NC, c = blk % NC;
    const int b = bh / H, h = bh % H;
    const long base = ((long)b * S + (long)c * L) * RS + h * D;

    const int tid = threadIdx.x;
    const int i = tid >> 3;
    const int u = (tid & 7) * 4;
    const int wv = i >> 3;           // sub-block id (wave-uniform)
    const long roff = base + (long)i * RS + u;

    float4 q4 = *(const float4*)(Qp + roff);
    float4 k4 = *(const float4*)(Kp + roff);
    float4 v4 = *(const float4*)(Vp + roff);
    float4 g4 = *(const float4*)(Gp + roff);
    float4 s04 = *(const float4*)(S0b + (long)(bh * NC + c) * (D * D) + tid * 4);

    *(float4*)&q_s[i][u] = q4;
    kts.kT[u + 0][i] = k4.x; kts.kT[u + 1][i] = k4.y;
    kts.kT[u + 2][i] = k4.z; kts.kT[u + 3][i] = k4.w;
    *(float4*)&w_s[i][u] = v4;
    float4 lv;
    lv.x = flog2(fmaxf(g4.x, GEPS));
    lv.y = flog2(fmaxf(g4.y, GEPS));
    lv.z = flog2(fmaxf(g4.z, GEPS));
    lv.w = flog2(fmaxf(g4.w, GEPS));
    *(float4*)&l_s[i][u] = lv;
    __syncthreads();                               // b1

    // --- phase A: column subtotals + q-row preload + A-matmul ---
    const int m = tid & 31, t = tid >> 5;
    const int r0 = t * 4;
    float c0 = l_s[r0 + 0][m];
    float c1 = c0 + l_s[r0 + 1][m];
    float c2 = c1 + l_s[r0 + 2][m];
    float c3 = c2 + l_s[r0 + 3][m];
    sub[t][m] = c3;

    // own q row into registers (reused by A-matmul and S0-dot)
    float4 tq[8];
    #pragma unroll
    for (int dd = 0; dd < 8; ++dd) tq[dd] = *(float4*)&q_s[i][dd * 4];

    // A[i][u..u+3] = q_i . k_j (unmasked; consumers use j<=i only)
    {
        float4 a = {0, 0, 0, 0};
        #pragma unroll
        for (int dd = 0; dd < 8; ++dd) {
            #pragma unroll
            for (int cc = 0; cc < 4; ++cc) {
                const float qv = (&tq[dd].x)[cc];
                const int d = dd * 4 + cc;
                a.x += qv * kts.kT[d][u + 0];
                a.y += qv * kts.kT[d][u + 1];
                a.z += qv * kts.kT[d][u + 2];
                a.w += qv * kts.kT[d][u + 3];
            }
        }
        a_s[i][u + 0] = a.x; a_s[i][u + 1] = a.y;
        a_s[i][u + 2] = a.z; a_s[i][u + 3] = a.w;
    }
    __syncthreads();                               // b2  (kT dead from here)

    // --- phase B: finalize l (in place), scale W (in place), stage S0 ---
    {
        float sb[8];
        #pragma unroll
        for (int tt = 0; tt < 8; ++tt) sb[tt] = sub[tt][m];
        float base_l = 0.f;
        #pragma unroll
        for (int tt = 0; tt < 8; ++tt) { if (tt < t) base_l += sb[tt]; }
        float es_own = 0.f;          // l at end of this group's sub-block
        const int tcap = t | 1;
        #pragma unroll
        for (int tt = 0; tt < 8; ++tt) { if (tt <= tcap) es_own += sb[tt]; }
        const float l0 = base_l + c0, l1 = base_l + c1,
                    l2 = base_l + c2, l3 = base_l + c3;
        l_s[r0 + 0][m] = l0; l_s[r0 + 1][m] = l1;
        l_s[r0 + 2][m] = l2; l_s[r0 + 3][m] = l3;
        // W = v * 2^{e_s - l}  (exponent <= 0)
        w_s[r0 + 0][m] *= fexp2(es_own - l0);
        w_s[r0 + 1][m] *= fexp2(es_own - l1);
        w_s[r0 + 2][m] *= fexp2(es_own - l2);
        w_s[r0 + 3][m] *= fexp2(es_own - l3);
    }
    *(float4*)&kts.s0[tid >> 3][(tid & 7) * 4] = s04;   // stage S0 into old kT slot
    __syncthreads();                               // b3

    // --- phase C: outputs ---
    const float4 val = *(float4*)&l_s[i][u];       // final l_i

    // cross-chunk: 2^{l_i} * (q_i . S0[:,m])  -- q from registers
    float4 o = {0, 0, 0, 0};
    #pragma unroll
    for (int dd = 0; dd < 8; ++dd) {
        #pragma unroll
        for (int cc = 0; cc < 4; ++cc) {
            const float qv = (&tq[dd].x)[cc];
            float4 s4 = *(float4*)&kts.s0[dd * 4 + cc][u];
            o.x += qv * s4.x; o.y += qv * s4.y; o.z += qv * s4.z; o.w += qv * s4.w;
        }
    }
    o.x *= fexp2(val.x); o.y *= fexp2(val.y);
    o.z *= fexp2(val.z); o.w *= fexp2(val.w);

    // intra-chunk, sub-block factorized; RUNTIME loop bound (wave-uniform)
    for (int s = 0; s <= wv; ++s) {
        float4 tc = {0, 0, 0, 0};
        const int jb = s << 3;
        if (s < wv) {
            #pragma unroll
            for (int jj = 0; jj < 8; ++jj) {
                const float av = a_s[i][jb + jj];
                float4 w = *(float4*)&w_s[jb + jj][u];
                tc.x += av * w.x; tc.y += av * w.y;
                tc.z += av * w.z; tc.w += av * w.w;
            }
        } else {
            #pragma unroll
            for (int jj = 0; jj < 8; ++jj) {
                const int j = jb + jj;
                const float av = (j <= i) ? a_s[i][j] : 0.f;
                float4 w = *(float4*)&w_s[j][u];
                tc.x += av * w.x; tc.y += av * w.y;
                tc.z += av * w.z; tc.w += av * w.w;
            }
        }
        float4 e4 = *(float4*)&l_s[jb + 7][u];
        // s<wv: exponent <= 0; s==wv: in [0,112] -> finite
        o.x += fexp2(val.x - e4.x) * tc.x;
        o.y += fexp2(val.y - e4.y) * tc.y;
        o.z += fexp2(val.z - e4.z) * tc.z;
        o.w += fexp2(val.w - e4.w) * tc.w;
    }

    *(float4*)(Op + roff) = o;
}

} // namespace

extern "C" void kernel_launch(void* const* d_in, const int* in_sizes, int n_in,
                              void* d_out, int out_size, void* d_ws, size_t ws_size,
                              hipStream_t stream)
{
    const float* q = (const float*)d_in[0];
    const float* k = (const float*)d_in[1];
    const float* v = (const float*)d_in[2];
    const float* g = (const float*)d_in[3];
    float* out = (float*)d_out;

    float* KVb = (float*)d_ws;                       // [NBH][NC][D][D]  (33.55 MB)
    float* Gb = KVb + (long)NBH * NC * D * D;        // [NBH][NC][D]     (1.05 MB)

    dim3 blk(256);
    k1_chunk_summary<<<dim3(NBH * NC), blk, 0, stream>>>(k, v, g, KVb, Gb);
    k2_scan<<<dim3(NBH * 4), blk, 0, stream>>>(KVb, Gb);
    k3_out<<<dim3(NBH * NC), blk, 0, stream>>>(q, k, v, g, KVb, out);
}

// Round 12
// 73.898 us; speedup vs baseline: 4.0967x; 1.2523x over previous
//
#include <hip/hip_runtime.h>

namespace {

constexpr int B = 4, S = 4096, H = 16, D = 32;
constexpr int L = 32;             // chunk length
constexpr int NC = S / L;         // 128 chunks per sequence
constexpr int NBH = B * H;        // 64
constexpr int RS = H * D;         // 512 floats between consecutive time steps
constexpr int PW = 36;            // padded LDS row width (f32 arrays)
constexpr float GEPS = 1.52587890625e-05f;  // 2^-16 per-step decay clamp
                                            // (max 7 steps to sub-block end * 16 = 112 < 126)

// Lore (rounds 6-11, measured):
//  - launch_bounds(256,w) caps VGPR ~256/w; cap < live set => GB-scale spill.
//  - r11 arithmetic: scalar k3 was LDS-INSTRUCTION-throughput bound
//    (~105 LDS instrs/lane ~= 58us at 12cy/b128) -> MFMA (register operands)
//    is the only way past it, not occupancy tuning.

typedef __attribute__((ext_vector_type(8)))  short short8v;   // 8 bf16 = 4 VGPR
typedef __attribute__((ext_vector_type(16))) float f32x16;    // 16 f32 acc

__device__ __forceinline__ float flog2(float x) { return __builtin_amdgcn_logf(x); }
__device__ __forceinline__ float fexp2(float x) { return __builtin_amdgcn_exp2f(x); }
__device__ __forceinline__ short f2bf(float f) {              // fp32 -> bf16 (RNE)
    unsigned u = __float_as_uint(f);
    u = (u + 0x7FFFu + ((u >> 16) & 1u)) >> 16;
    return (short)u;
}

// ---------------- Kernel 1: per-chunk summaries (unchanged, verified) ----------
__global__ __launch_bounds__(256)
void k1_chunk_summary(const float* __restrict__ Kp, const float* __restrict__ Vp,
                      const float* __restrict__ Gp, float* __restrict__ KVb,
                      float* __restrict__ Gb)
{
    __shared__ float k_s[L][PW];
    __shared__ float w_s[L][PW];
    __shared__ float lg[L][PW];
    __shared__ float sub[8][D];

    const int blk = blockIdx.x;
    const int bh = blk / NC, c = blk % NC;
    const int b = bh / H, h = bh % H;
    const long base = ((long)b * S + (long)c * L) * RS + h * D;

    const int tid = threadIdx.x;
    const int i = tid >> 3;
    const int u = (tid & 7) * 4;
    const long roff = base + (long)i * RS + u;

    float4 k4 = *(const float4*)(Kp + roff);
    float4 v4 = *(const float4*)(Vp + roff);
    float4 g4 = *(const float4*)(Gp + roff);
    *(float4*)&k_s[i][u] = k4;
    *(float4*)&w_s[i][u] = v4;
    float4 lv;
    lv.x = flog2(fmaxf(g4.x, GEPS));
    lv.y = flog2(fmaxf(g4.y, GEPS));
    lv.z = flog2(fmaxf(g4.z, GEPS));
    lv.w = flog2(fmaxf(g4.w, GEPS));
    *(float4*)&lg[i][u] = lv;
    __syncthreads();

    const int m = tid & 31, t = tid >> 5;
    const int r0 = t * 4;
    float c0 = lg[r0 + 0][m];
    float c1 = c0 + lg[r0 + 1][m];
    float c2 = c1 + lg[r0 + 2][m];
    float c3 = c2 + lg[r0 + 3][m];
    sub[t][m] = c3;
    __syncthreads();

    float sb[8];
    float total = 0.f;
    #pragma unroll
    for (int tt = 0; tt < 8; ++tt) { sb[tt] = sub[tt][m]; total += sb[tt]; }
    float base_l = 0.f;
    #pragma unroll
    for (int tt = 0; tt < 8; ++tt) { if (tt < t) base_l += sb[tt]; }
    w_s[r0 + 0][m] *= fexp2(total - (base_l + c0));
    w_s[r0 + 1][m] *= fexp2(total - (base_l + c1));
    w_s[r0 + 2][m] *= fexp2(total - (base_l + c2));
    w_s[r0 + 3][m] *= fexp2(total - (base_l + c3));
    if (t == 0) Gb[(long)(bh * NC + c) * D + m] = fexp2(total);
    __syncthreads();

    const int d = tid >> 3;
    const int mg = (tid & 7) * 4;
    float4 acc = {0, 0, 0, 0};
    #pragma unroll
    for (int j = 0; j < L; ++j) {
        float kv = k_s[j][d];
        float4 w = *(float4*)&w_s[j][mg];
        acc.x += kv * w.x; acc.y += kv * w.y; acc.z += kv * w.z; acc.w += kv * w.w;
    }
    *(float4*)(KVb + (long)(bh * NC + c) * (D * D) + d * D + mg) = acc;
}

// ---------------- Kernel 2: inter-chunk scan (unchanged, verified) ------------
__global__ __launch_bounds__(256)
void k2_scan(float* __restrict__ KVb, const float* __restrict__ Gb)
{
    const int bh = blockIdx.x >> 2;
    const int dg = blockIdx.x & 3;
    const int tid = threadIdx.x;
    const int d = dg * 8 + (tid >> 5);
    const int m = tid & 31;

    const long kvoff = (long)bh * NC * (D * D) + d * D + m;
    const long goff = (long)bh * NC * D + m;

    float ka[8], ga[8];
    #pragma unroll
    for (int t = 0; t < 8; ++t) {
        ka[t] = KVb[kvoff + (long)t * (D * D)];
        ga[t] = Gb[goff + (long)t * D];
    }
    float st = 0.f;
    for (int c0 = 0; c0 < NC; c0 += 8) {
        float kb[8], gb2[8];
        const bool more = (c0 + 8) < NC;
        #pragma unroll
        for (int t = 0; t < 8; ++t) {
            kb[t]  = more ? KVb[kvoff + (long)(c0 + 8 + t) * (D * D)] : 0.f;
            gb2[t] = more ? Gb[goff + (long)(c0 + 8 + t) * D] : 0.f;
        }
        #pragma unroll
        for (int t = 0; t < 8; ++t) {
            KVb[kvoff + (long)(c0 + t) * (D * D)] = st;
            st = ga[t] * st + ka[t];
        }
        #pragma unroll
        for (int t = 0; t < 8; ++t) { ka[t] = kb[t]; ga[t] = gb2[t]; }
    }
}

// ---------------- Kernel 3: MFMA per-chunk outputs ----------------------------
// One wave per chunk; 4 chunks per block.
// out_i[m] = 2^{l_i[m]} (q_i . S0[:,m])
//          + sum_s 2^{l_i[m]-e_s[m]} sum_{j in s, j<=i} A_ij W_j[m]
// A = QK^T (MFMA), P_s = Amask_s . W (MFMA), QS0 (MFMA). W,A stored bf16 in LDS.
// Layouts (gfx950 v_mfma_f32_32x32x16_bf16):
//   A-op: row i = lane&31, k = 8*(lane>>5)+e   B-op: col j = lane&31, same k
//   C/D : col m = lane&31, row = (reg&3)+8*(reg>>2)+4*(lane>>5)  [HW-verified]
__global__ __launch_bounds__(256)
void k3_mfma(const float* __restrict__ Qp, const float* __restrict__ Kp,
             const float* __restrict__ Vp, const float* __restrict__ Gp,
             const float* __restrict__ S0b, float* __restrict__ Op)
{
    __shared__ __align__(16) float  l_s[4][L][PW];   // final cumlog, f32
    __shared__ __align__(16) ushort w_s[4][L][40];   // W bf16, row-major
    __shared__ __align__(16) ushort a_s[4][L][40];   // masked A bf16, row-major
    __shared__ float tot[4][D];

    const int tid = threadIdx.x;
    const int wv = tid >> 6;           // wave id = chunk-within-block
    const int lane = tid & 63;
    const int half = lane >> 5;
    const int m = lane & 31;

    const int chunk = blockIdx.x * 4 + wv;          // == bh*NC + c
    const int bh = chunk >> 7;
    const int c = chunk & (NC - 1);
    const int b = bh >> 4;
    const int h = bh & (H - 1);
    const long base = ((long)b * S + (long)c * L) * RS + h * D;
    const float* S0c = S0b + (long)chunk * (D * D);

    // ---- Q/K fragment loads: direct from global in operand layout ----
    const float* qrow = Qp + base + (long)m * RS + 8 * half;
    const float* krow = Kp + base + (long)m * RS + 8 * half;
    float4 qv0 = *(const float4*)(qrow);
    float4 qv1 = *(const float4*)(qrow + 4);
    float4 qv2 = *(const float4*)(qrow + 16);
    float4 qv3 = *(const float4*)(qrow + 20);
    float4 kv0 = *(const float4*)(krow);
    float4 kv1 = *(const float4*)(krow + 4);
    float4 kv2 = *(const float4*)(krow + 16);
    float4 kv3 = *(const float4*)(krow + 20);
    short8v qa0, qa1, ka0, ka1;
    {
        float qf[16] = {qv0.x,qv0.y,qv0.z,qv0.w, qv1.x,qv1.y,qv1.z,qv1.w,
                        qv2.x,qv2.y,qv2.z,qv2.w, qv3.x,qv3.y,qv3.z,qv3.w};
        float kf[16] = {kv0.x,kv0.y,kv0.z,kv0.w, kv1.x,kv1.y,kv1.z,kv1.w,
                        kv2.x,kv2.y,kv2.z,kv2.w, kv3.x,kv3.y,kv3.z,kv3.w};
        #pragma unroll
        for (int e = 0; e < 8; ++e) {
            qa0[e] = f2bf(qf[e]);     qa1[e] = f2bf(qf[8 + e]);
            ka0[e] = f2bf(kf[e]);     ka1[e] = f2bf(kf[8 + e]);
        }
    }

    // ---- scan: lane owns column m, rows half*16..+15 (register cumsum) ----
    float cum[16];
    {
        const float* gcol = Gp + base + (long)(half * 16) * RS + m;
        float run = 0.f;
        #pragma unroll
        for (int t = 0; t < 16; ++t) {
            run += flog2(fmaxf(gcol[(long)t * RS], GEPS));
            cum[t] = run;
        }
    }
    if (half == 0) tot[wv][m] = cum[15];
    __syncthreads();                                 // b1
    {
        const float basel = (half == 1) ? tot[wv][m] : 0.f;
        #pragma unroll
        for (int t = 0; t < 16; ++t) cum[t] += basel;
    }
    const float e_a = cum[7], e_b = cum[15];         // own two sub-block ends

    // ---- W = v * 2^{e_s(j)-l_j} (<=1), bf16; write l_s ----
    {
        const float* vcol = Vp + base + (long)(half * 16) * RS + m;
        #pragma unroll
        for (int t = 0; t < 16; ++t) {
            const int r = half * 16 + t;
            const float e = (t < 8) ? e_a : e_b;
            const float w = vcol[(long)t * RS] * fexp2(e - cum[t]);
            w_s[wv][r][m] = (ushort)f2bf(w);
            l_s[wv][r][m] = cum[t];
        }
    }
    __syncthreads();                                 // b2: l_s, w_s ready

    // ---- Gram A = Q.K^T, causal-mask, store bf16 ----
    f32x16 acc;
    #pragma unroll
    for (int e = 0; e < 16; ++e) acc[e] = 0.f;
    acc = __builtin_amdgcn_mfma_f32_32x32x16_bf16(qa0, ka0, acc, 0, 0, 0);
    acc = __builtin_amdgcn_mfma_f32_32x32x16_bf16(qa1, ka1, acc, 0, 0, 0);
    #pragma unroll
    for (int reg = 0; reg < 16; ++reg) {
        const int irow = (reg & 3) + 8 * (reg >> 2) + 4 * half;
        const float av = (m <= irow) ? acc[reg] : 0.f;
        a_s[wv][irow][m] = (ushort)f2bf(av);
    }
    __syncthreads();                                 // b3: a_s ready

    // ---- per-lane l_i / e_s (D-fragment rows) ----
    float li[16];
    #pragma unroll
    for (int reg = 0; reg < 16; ++reg)
        li[reg] = l_s[wv][(reg & 3) + 8 * (reg >> 2) + 4 * half][m];
    float es4[4];
    #pragma unroll
    for (int s = 0; s < 4; ++s) es4[s] = l_s[wv][8 * s + 7][m];

    // ---- cross-chunk: 2^{l_i} * (Q . S0) ----
    f32x16 sacc;
    #pragma unroll
    for (int e = 0; e < 16; ++e) sacc[e] = 0.f;
    {
        short8v sf0, sf1;
        #pragma unroll
        for (int e = 0; e < 8; ++e) {
            sf0[e] = f2bf(S0c[(8 * half + e) * D + m]);
            sf1[e] = f2bf(S0c[(16 + 8 * half + e) * D + m]);
        }
        sacc = __builtin_amdgcn_mfma_f32_32x32x16_bf16(qa0, sf0, sacc, 0, 0, 0);
        sacc = __builtin_amdgcn_mfma_f32_32x32x16_bf16(qa1, sf1, sacc, 0, 0, 0);
    }
    f32x16 out;
    #pragma unroll
    for (int reg = 0; reg < 16; ++reg) out[reg] = fexp2(li[reg]) * sacc[reg];

    // ---- intra: P_s = Amask_s . W, scaled accumulate ----
    #pragma unroll
    for (int ks = 0; ks < 2; ++ks) {
        const short8v af = *(const short8v*)&a_s[wv][m][16 * ks + 8 * half];
        short8v wf;
        #pragma unroll
        for (int e = 0; e < 8; ++e)
            wf[e] = (short)w_s[wv][16 * ks + 8 * half + e][m];
        #pragma unroll
        for (int par = 0; par < 2; ++par) {
            const int s = 2 * ks + par;
            short8v am;
            #pragma unroll
            for (int e = 0; e < 8; ++e) am[e] = (half == par) ? af[e] : (short)0;
            f32x16 p;
            #pragma unroll
            for (int e = 0; e < 16; ++e) p[e] = 0.f;
            p = __builtin_amdgcn_mfma_f32_32x32x16_bf16(am, wf, p, 0, 0, 0);
            // s == s(i): exponent in [0,112]; s < s(i): <= 0; s > s(i): p==0 and
            // clamp 120 keeps the (unused) scale finite -> 0 * finite = 0.
            #pragma unroll
            for (int reg = 0; reg < 16; ++reg)
                out[reg] += fexp2(fminf(li[reg] - es4[s], 120.f)) * p[reg];
        }
    }

    // ---- store ----
    #pragma unroll
    for (int reg = 0; reg < 16; ++reg) {
        const int irow = (reg & 3) + 8 * (reg >> 2) + 4 * half;
        Op[base + (long)irow * RS + m] = out[reg];
    }
}

} // namespace

extern "C" void kernel_launch(void* const* d_in, const int* in_sizes, int n_in,
                              void* d_out, int out_size, void* d_ws, size_t ws_size,
                              hipStream_t stream)
{
    const float* q = (const float*)d_in[0];
    const float* k = (const float*)d_in[1];
    const float* v = (const float*)d_in[2];
    const float* g = (const float*)d_in[3];
    float* out = (float*)d_out;

    float* KVb = (float*)d_ws;                       // [NBH][NC][D][D]  (33.55 MB)
    float* Gb = KVb + (long)NBH * NC * D * D;        // [NBH][NC][D]     (1.05 MB)

    dim3 blk(256);
    k1_chunk_summary<<<dim3(NBH * NC), blk, 0, stream>>>(k, v, g, KVb, Gb);
    k2_scan<<<dim3(NBH * 4), blk, 0, stream>>>(KVb, Gb);
    k3_mfma<<<dim3(NBH * NC / 4), blk, 0, stream>>>(q, k, v, g, KVb, out);
}

// Round 13
// 73.882 us; speedup vs baseline: 4.0976x; 1.0002x over previous
//
#include <hip/hip_runtime.h>

namespace {

constexpr int B = 4, S = 4096, H = 16, D = 32;
constexpr int L = 32;             // chunk length
constexpr int NC = S / L;         // 128 chunks per sequence
constexpr int NBH = B * H;        // 64
constexpr int RS = H * D;         // 512 floats between consecutive time steps
constexpr float GEPS = 1.52587890625e-05f;  // 2^-16 per-step decay clamp

// Lore (rounds 6-12, measured):
//  - launch_bounds(256,w) caps VGPR ~256/w; cap < live set => GB-scale spill.
//  - Scalar j-loops over LDS tiles are LDS-INSTRUCTION-throughput bound
//    (~12cy per b128): both old k3 (58us) and old k1 (30us of its 39.6)
//    -> replace 32x32 matmuls with v_mfma_f32_32x32x16_bf16.
//  - MFMA operand convention (HW-verified via round-12 pass, absmax 0.5):
//    A-op: row = lane&31, k = 8*(lane>>5)+e (+16 for 2nd MFMA)
//    B-op: col = lane&31, same k      C/D: col=lane&31, row=(reg&3)+8*(reg>>2)+4*(lane>>5)

typedef __attribute__((ext_vector_type(8)))  short short8v;   // 8 bf16 = 4 VGPR
typedef __attribute__((ext_vector_type(16))) float f32x16;    // 16 f32 acc

__device__ __forceinline__ float flog2(float x) { return __builtin_amdgcn_logf(x); }
__device__ __forceinline__ float fexp2(float x) { return __builtin_amdgcn_exp2f(x); }
__device__ __forceinline__ short f2bf(float f) {              // fp32 -> bf16 (RNE)
    unsigned u = __float_as_uint(f);
    u = (u + 0x7FFFu + ((u >> 16) & 1u)) >> 16;
    return (short)u;
}

// ---------------- Kernel 1: MFMA per-chunk summaries --------------------------
// One wave per chunk; 4 chunks per block.
// l = cumsum log2(max(g,GEPS)) (per-lane register scan of own column)
// W_j[m] = v_j[m]*2^{l_end[m]-l_j[m]} (<=1), bf16
// KVb[chunk][d][m] = sum_j K[j][d]*W[j][m]  (2 MFMAs)
// Gb[chunk][m] = 2^{l_end[m]}
__global__ __launch_bounds__(256)
void k1_mfma(const float* __restrict__ Kp, const float* __restrict__ Vp,
             const float* __restrict__ Gp, float* __restrict__ KVb,
             float* __restrict__ Gb)
{
    __shared__ ushort w_s[4][L][40];   // W bf16
    __shared__ float tot0[4][D];
    __shared__ float tot1[4][D];

    const int tid = threadIdx.x;
    const int wv = tid >> 6;
    const int lane = tid & 63;
    const int half = lane >> 5;
    const int m = lane & 31;

    const int chunk = blockIdx.x * 4 + wv;          // == bh*NC + c
    const int bh = chunk >> 7;
    const int c = chunk & (NC - 1);
    const int b = bh >> 4;
    const int h = bh & (H - 1);
    const long base = ((long)b * S + (long)c * L) * RS + h * D;

    // K A-fragment: A[d=m][k=j] = K[j][m]  (column loads, coalesced across lanes)
    short8v ka0, ka1;
    {
        const float* kcol = Kp + base + m;
        #pragma unroll
        for (int e = 0; e < 8; ++e) {
            ka0[e] = f2bf(kcol[(long)(8 * half + e) * RS]);
            ka1[e] = f2bf(kcol[(long)(16 + 8 * half + e) * RS]);
        }
    }

    // register cumsum of own column (rows half*16 .. half*16+15)
    float cum[16];
    {
        const float* gcol = Gp + base + (long)(half * 16) * RS + m;
        float run = 0.f;
        #pragma unroll
        for (int t = 0; t < 16; ++t) {
            run += flog2(fmaxf(gcol[(long)t * RS], GEPS));
            cum[t] = run;
        }
    }
    if (half == 0) tot0[wv][m] = cum[15];
    __syncthreads();                               // b1
    if (half == 1) {
        const float b0 = tot0[wv][m];
        #pragma unroll
        for (int t = 0; t < 16; ++t) cum[t] += b0;
        tot1[wv][m] = cum[15];
    }
    __syncthreads();                               // b2
    const float total = tot1[wv][m];

    // W = v * 2^{total - l}  (exponent <= 0), bf16 into LDS
    {
        const float* vcol = Vp + base + (long)(half * 16) * RS + m;
        #pragma unroll
        for (int t = 0; t < 16; ++t) {
            const float w = vcol[(long)t * RS] * fexp2(total - cum[t]);
            w_s[wv][half * 16 + t][m] = (ushort)f2bf(w);
        }
    }
    if (half == 1) Gb[(long)chunk * D + m] = fexp2(total);
    __syncthreads();                               // b3

    // B-fragment from LDS, 2 MFMAs, coalesced store
    short8v wf0, wf1;
    #pragma unroll
    for (int e = 0; e < 8; ++e) {
        wf0[e] = (short)w_s[wv][8 * half + e][m];
        wf1[e] = (short)w_s[wv][16 + 8 * half + e][m];
    }
    f32x16 acc;
    #pragma unroll
    for (int e = 0; e < 16; ++e) acc[e] = 0.f;
    acc = __builtin_amdgcn_mfma_f32_32x32x16_bf16(ka0, wf0, acc, 0, 0, 0);
    acc = __builtin_amdgcn_mfma_f32_32x32x16_bf16(ka1, wf1, acc, 0, 0, 0);

    float* kvout = KVb + (long)chunk * (D * D);
    #pragma unroll
    for (int reg = 0; reg < 16; ++reg) {
        const int d = (reg & 3) + 8 * (reg >> 2) + 4 * half;
        kvout[d * D + m] = acc[reg];
    }
}

// ---------------- Kernel 2: inter-chunk scan (unchanged, verified) ------------
__global__ __launch_bounds__(256)
void k2_scan(float* __restrict__ KVb, const float* __restrict__ Gb)
{
    const int bh = blockIdx.x >> 2;
    const int dg = blockIdx.x & 3;
    const int tid = threadIdx.x;
    const int d = dg * 8 + (tid >> 5);
    const int m = tid & 31;

    const long kvoff = (long)bh * NC * (D * D) + d * D + m;
    const long goff = (long)bh * NC * D + m;

    float ka[8], ga[8];
    #pragma unroll
    for (int t = 0; t < 8; ++t) {
        ka[t] = KVb[kvoff + (long)t * (D * D)];
        ga[t] = Gb[goff + (long)t * D];
    }
    float st = 0.f;
    for (int c0 = 0; c0 < NC; c0 += 8) {
        float kb[8], gb2[8];
        const bool more = (c0 + 8) < NC;
        #pragma unroll
        for (int t = 0; t < 8; ++t) {
            kb[t]  = more ? KVb[kvoff + (long)(c0 + 8 + t) * (D * D)] : 0.f;
            gb2[t] = more ? Gb[goff + (long)(c0 + 8 + t) * D] : 0.f;
        }
        #pragma unroll
        for (int t = 0; t < 8; ++t) {
            KVb[kvoff + (long)(c0 + t) * (D * D)] = st;
            st = ga[t] * st + ka[t];
        }
        #pragma unroll
        for (int t = 0; t < 8; ++t) { ka[t] = kb[t]; ga[t] = gb2[t]; }
    }
}

// ---------------- Kernel 3: MFMA per-chunk outputs (unchanged, verified) ------
__global__ __launch_bounds__(256)
void k3_mfma(const float* __restrict__ Qp, const float* __restrict__ Kp,
             const float* __restrict__ Vp, const float* __restrict__ Gp,
             const float* __restrict__ S0b, float* __restrict__ Op)
{
    __shared__ __align__(16) float  l_s[4][L][36];   // final cumlog, f32
    __shared__ __align__(16) ushort w_s[4][L][40];   // W bf16, row-major
    __shared__ __align__(16) ushort a_s[4][L][40];   // masked A bf16, row-major
    __shared__ float tot[4][D];

    const int tid = threadIdx.x;
    const int wv = tid >> 6;
    const int lane = tid & 63;
    const int half = lane >> 5;
    const int m = lane & 31;

    const int chunk = blockIdx.x * 4 + wv;
    const int bh = chunk >> 7;
    const int c = chunk & (NC - 1);
    const int b = bh >> 4;
    const int h = bh & (H - 1);
    const long base = ((long)b * S + (long)c * L) * RS + h * D;
    const float* S0c = S0b + (long)chunk * (D * D);

    // Q/K fragments direct from global
    const float* qrow = Qp + base + (long)m * RS + 8 * half;
    const float* krow = Kp + base + (long)m * RS + 8 * half;
    float4 qv0 = *(const float4*)(qrow);
    float4 qv1 = *(const float4*)(qrow + 4);
    float4 qv2 = *(const float4*)(qrow + 16);
    float4 qv3 = *(const float4*)(qrow + 20);
    float4 kv0 = *(const float4*)(krow);
    float4 kv1 = *(const float4*)(krow + 4);
    float4 kv2 = *(const float4*)(krow + 16);
    float4 kv3 = *(const float4*)(krow + 20);
    short8v qa0, qa1, ka0, ka1;
    {
        float qf[16] = {qv0.x,qv0.y,qv0.z,qv0.w, qv1.x,qv1.y,qv1.z,qv1.w,
                        qv2.x,qv2.y,qv2.z,qv2.w, qv3.x,qv3.y,qv3.z,qv3.w};
        float kf[16] = {kv0.x,kv0.y,kv0.z,kv0.w, kv1.x,kv1.y,kv1.z,kv1.w,
                        kv2.x,kv2.y,kv2.z,kv2.w, kv3.x,kv3.y,kv3.z,kv3.w};
        #pragma unroll
        for (int e = 0; e < 8; ++e) {
            qa0[e] = f2bf(qf[e]);     qa1[e] = f2bf(qf[8 + e]);
            ka0[e] = f2bf(kf[e]);     ka1[e] = f2bf(kf[8 + e]);
        }
    }

    // register cumsum of own column
    float cum[16];
    {
        const float* gcol = Gp + base + (long)(half * 16) * RS + m;
        float run = 0.f;
        #pragma unroll
        for (int t = 0; t < 16; ++t) {
            run += flog2(fmaxf(gcol[(long)t * RS], GEPS));
            cum[t] = run;
        }
    }
    if (half == 0) tot[wv][m] = cum[15];
    __syncthreads();                                 // b1
    {
        const float basel = (half == 1) ? tot[wv][m] : 0.f;
        #pragma unroll
        for (int t = 0; t < 16; ++t) cum[t] += basel;
    }
    const float e_a = cum[7], e_b = cum[15];

    // W = v * 2^{e_s(j)-l_j} (<=1), bf16; write l_s
    {
        const float* vcol = Vp + base + (long)(half * 16) * RS + m;
        #pragma unroll
        for (int t = 0; t < 16; ++t) {
            const int r = half * 16 + t;
            const float e = (t < 8) ? e_a : e_b;
            const float w = vcol[(long)t * RS] * fexp2(e - cum[t]);
            w_s[wv][r][m] = (ushort)f2bf(w);
            l_s[wv][r][m] = cum[t];
        }
    }
    __syncthreads();                                 // b2

    // Gram A = Q.K^T, causal-mask, bf16
    f32x16 acc;
    #pragma unroll
    for (int e = 0; e < 16; ++e) acc[e] = 0.f;
    acc = __builtin_amdgcn_mfma_f32_32x32x16_bf16(qa0, ka0, acc, 0, 0, 0);
    acc = __builtin_amdgcn_mfma_f32_32x32x16_bf16(qa1, ka1, acc, 0, 0, 0);
    #pragma unroll
    for (int reg = 0; reg < 16; ++reg) {
        const int irow = (reg & 3) + 8 * (reg >> 2) + 4 * half;
        const float av = (m <= irow) ? acc[reg] : 0.f;
        a_s[wv][irow][m] = (ushort)f2bf(av);
    }
    __syncthreads();                                 // b3

    float li[16];
    #pragma unroll
    for (int reg = 0; reg < 16; ++reg)
        li[reg] = l_s[wv][(reg & 3) + 8 * (reg >> 2) + 4 * half][m];
    float es4[4];
    #pragma unroll
    for (int s = 0; s < 4; ++s) es4[s] = l_s[wv][8 * s + 7][m];

    // cross-chunk: 2^{l_i} * (Q . S0)
    f32x16 sacc;
    #pragma unroll
    for (int e = 0; e < 16; ++e) sacc[e] = 0.f;
    {
        short8v sf0, sf1;
        #pragma unroll
        for (int e = 0; e < 8; ++e) {
            sf0[e] = f2bf(S0c[(8 * half + e) * D + m]);
            sf1[e] = f2bf(S0c[(16 + 8 * half + e) * D + m]);
        }
        sacc = __builtin_amdgcn_mfma_f32_32x32x16_bf16(qa0, sf0, sacc, 0, 0, 0);
        sacc = __builtin_amdgcn_mfma_f32_32x32x16_bf16(qa1, sf1, sacc, 0, 0, 0);
    }
    f32x16 out;
    #pragma unroll
    for (int reg = 0; reg < 16; ++reg) out[reg] = fexp2(li[reg]) * sacc[reg];

    // intra: P_s = Amask_s . W, scaled accumulate
    #pragma unroll
    for (int ks = 0; ks < 2; ++ks) {
        const short8v af = *(const short8v*)&a_s[wv][m][16 * ks + 8 * half];
        short8v wf;
        #pragma unroll
        for (int e = 0; e < 8; ++e)
            wf[e] = (short)w_s[wv][16 * ks + 8 * half + e][m];
        #pragma unroll
        for (int par = 0; par < 2; ++par) {
            const int s = 2 * ks + par;
            short8v am;
            #pragma unroll
            for (int e = 0; e < 8; ++e) am[e] = (half == par) ? af[e] : (short)0;
            f32x16 p;
            #pragma unroll
            for (int e = 0; e < 16; ++e) p[e] = 0.f;
            p = __builtin_amdgcn_mfma_f32_32x32x16_bf16(am, wf, p, 0, 0, 0);
            #pragma unroll
            for (int reg = 0; reg < 16; ++reg)
                out[reg] += fexp2(fminf(li[reg] - es4[s], 120.f)) * p[reg];
        }
    }

    #pragma unroll
    for (int reg = 0; reg < 16; ++reg) {
        const int irow = (reg & 3) + 8 * (reg >> 2) + 4 * half;
        Op[base + (long)irow * RS + m] = out[reg];
    }
}

} // namespace

extern "C" void kernel_launch(void* const* d_in, const int* in_sizes, int n_in,
                              void* d_out, int out_size, void* d_ws, size_t ws_size,
                              hipStream_t stream)
{
    const float* q = (const float*)d_in[0];
    const float* k = (const float*)d_in[1];
    const float* v = (const float*)d_in[2];
    const float* g = (const float*)d_in[3];
    float* out = (float*)d_out;

    float* KVb = (float*)d_ws;                       // [NBH][NC][D][D]  (33.55 MB)
    float* Gb = KVb + (long)NBH * NC * D * D;        // [NBH][NC][D]     (1.05 MB)

    dim3 blk(256);
    k1_mfma<<<dim3(NBH * NC / 4), blk, 0, stream>>>(k, v, g, KVb, Gb);
    k2_scan<<<dim3(NBH * 4), blk, 0, stream>>>(KVb, Gb);
    k3_mfma<<<dim3(NBH * NC / 4), blk, 0, stream>>>(q, k, v, g, KVb, out);
}

// Round 14
// 73.765 us; speedup vs baseline: 4.1041x; 1.0016x over previous
//
#include <hip/hip_runtime.h>

namespace {

constexpr int B = 4, S = 4096, H = 16, D = 32;
constexpr int L = 32;             // chunk length
constexpr int NC = S / L;         // 128 chunks per sequence
constexpr int NBH = B * H;        // 64
constexpr int RS = H * D;         // 512 floats between consecutive time steps
constexpr float GEPS = 1.52587890625e-05f;  // 2^-16 per-step decay clamp

// Lore (rounds 6-13, measured):
//  - launch_bounds(256,w) caps VGPR ~256/w; cap < live set => GB-scale spill.
//  - Scalar j-loops over LDS tiles are LDS-instruction bound (~12cy/b128)
//    -> use v_mfma_f32_32x32x16_bf16 for every 32x32 matmul.
//  - Scalar COLUMN loads from global (stride RS) are latency death: r13's k1
//    did 48/lane -> 46us at 8% VALU. Row-wise float4 + LDS transpose wins.
//  - MFMA operand convention (HW-verified r12, absmax 0.5):
//    A-op: row = lane&31, k = 8*(lane>>5)+e (+16 for 2nd MFMA)
//    B-op: col = lane&31, same k
//    C/D : col = lane&31, row = (reg&3)+8*(reg>>2)+4*(lane>>5)

typedef __attribute__((ext_vector_type(8)))  short short8v;   // 8 bf16 = 4 VGPR
typedef __attribute__((ext_vector_type(16))) float f32x16;    // 16 f32 acc

__device__ __forceinline__ float flog2(float x) { return __builtin_amdgcn_logf(x); }
__device__ __forceinline__ float fexp2(float x) { return __builtin_amdgcn_exp2f(x); }
__device__ __forceinline__ unsigned f2bfu(float f) {          // fp32 -> bf16 (RNE)
    unsigned u = __float_as_uint(f);
    return (u + 0x7FFFu + ((u >> 16) & 1u)) >> 16;
}
__device__ __forceinline__ short f2bf(float f) { return (short)f2bfu(f); }

// ---------------- Kernel 1: staged loads + column scan + MFMA tail ------------
// One block per chunk (8192 blocks).
// l = cumsum log2(max(g,GEPS)) (LDS column scan, 4-row groups)
// W[i][m] = v[i][m]*2^{total[m]-l_i[m]}  -- elementwise in ROW layout (v in regs)
// KVb[chunk][d][m] = sum_j K[j][d]*W[j][m]   (wave 0: 2 MFMAs)
// Gb[chunk][m] = 2^{total[m]}
__global__ __launch_bounds__(256)
void k1_stage(const float* __restrict__ Kp, const float* __restrict__ Vp,
              const float* __restrict__ Gp, float* __restrict__ KVb,
              float* __restrict__ Gb)
{
    __shared__ __align__(16) float  k_s[L][36];   // K f32 (column-read by wave 0)
    __shared__ __align__(16) float  lg[L][36];    // log2(g) -> final l in place
    __shared__ __align__(16) ushort w_s[L][40];   // W bf16
    __shared__ float sub[8][D];
    __shared__ float totr[D];

    const int blk = blockIdx.x;                   // == chunk == bh*NC + c
    const int bh = blk >> 7;
    const int c = blk & (NC - 1);
    const int b = bh >> 4;
    const int h = bh & (H - 1);
    const long base = ((long)b * S + (long)c * L) * RS + h * D;

    const int tid = threadIdx.x;
    const int i = tid >> 3;          // row 0..31
    const int u = (tid & 7) * 4;     // col quad
    const long roff = base + (long)i * RS + u;

    float4 k4 = *(const float4*)(Kp + roff);
    float4 v4 = *(const float4*)(Vp + roff);
    float4 g4 = *(const float4*)(Gp + roff);
    *(float4*)&k_s[i][u] = k4;
    float4 lv;
    lv.x = flog2(fmaxf(g4.x, GEPS));
    lv.y = flog2(fmaxf(g4.y, GEPS));
    lv.z = flog2(fmaxf(g4.z, GEPS));
    lv.w = flog2(fmaxf(g4.w, GEPS));
    *(float4*)&lg[i][u] = lv;
    __syncthreads();                               // b1

    // column scan: thread -> (column m, 4-row group t)
    const int m = tid & 31, t = tid >> 5;
    const int r0 = t * 4;
    float c0 = lg[r0 + 0][m];
    float c1 = c0 + lg[r0 + 1][m];
    float c2 = c1 + lg[r0 + 2][m];
    float c3 = c2 + lg[r0 + 3][m];
    sub[t][m] = c3;
    __syncthreads();                               // b2

    {
        float sb[8];
        float total = 0.f;
        #pragma unroll
        for (int tt = 0; tt < 8; ++tt) { sb[tt] = sub[tt][m]; total += sb[tt]; }
        float base_l = 0.f;
        #pragma unroll
        for (int tt = 0; tt < 8; ++tt) { if (tt < t) base_l += sb[tt]; }
        lg[r0 + 0][m] = base_l + c0;
        lg[r0 + 1][m] = base_l + c1;
        lg[r0 + 2][m] = base_l + c2;
        lg[r0 + 3][m] = base_l + c3;
        if (t == 0) totr[m] = total;
        if (t == 1) Gb[(long)blk * D + m] = fexp2(total);
    }
    __syncthreads();                               // b3

    // W elementwise in row layout: v4 still in registers
    {
        float4 l4 = *(float4*)&lg[i][u];
        float4 t4 = *(float4*)&totr[u];            // broadcast across rows
        unsigned p0 = f2bfu(v4.x * fexp2(t4.x - l4.x))
                    | (f2bfu(v4.y * fexp2(t4.y - l4.y)) << 16);
        unsigned p1 = f2bfu(v4.z * fexp2(t4.z - l4.z))
                    | (f2bfu(v4.w * fexp2(t4.w - l4.w)) << 16);
        uint2 pp; pp.x = p0; pp.y = p1;
        *(uint2*)&w_s[i][u] = pp;                  // 8B store, 8B-aligned (row=80B)
    }
    __syncthreads();                               // b4

    // wave 0: fragments + 2 MFMAs + store (waves 1-3 retire)
    if (tid < 64) {
        const int half = tid >> 5;
        const int mm = tid & 31;
        short8v ka0, ka1, wf0, wf1;
        #pragma unroll
        for (int e = 0; e < 8; ++e) {
            ka0[e] = f2bf(k_s[8 * half + e][mm]);
            ka1[e] = f2bf(k_s[16 + 8 * half + e][mm]);
            wf0[e] = (short)w_s[8 * half + e][mm];
            wf1[e] = (short)w_s[16 + 8 * half + e][mm];
        }
        f32x16 acc;
        #pragma unroll
        for (int e = 0; e < 16; ++e) acc[e] = 0.f;
        acc = __builtin_amdgcn_mfma_f32_32x32x16_bf16(ka0, wf0, acc, 0, 0, 0);
        acc = __builtin_amdgcn_mfma_f32_32x32x16_bf16(ka1, wf1, acc, 0, 0, 0);

        float* kvout = KVb + (long)blk * (D * D);
        #pragma unroll
        for (int reg = 0; reg < 16; ++reg) {
            const int d = (reg & 3) + 8 * (reg >> 2) + 4 * half;
            kvout[d * D + mm] = acc[reg];
        }
    }
}

// ---------------- Kernel 2: inter-chunk scan (unchanged, verified) ------------
__global__ __launch_bounds__(256)
void k2_scan(float* __restrict__ KVb, const float* __restrict__ Gb)
{
    const int bh = blockIdx.x >> 2;
    const int dg = blockIdx.x & 3;
    const int tid = threadIdx.x;
    const int d = dg * 8 + (tid >> 5);
    const int m = tid & 31;

    const long kvoff = (long)bh * NC * (D * D) + d * D + m;
    const long goff = (long)bh * NC * D + m;

    float ka[8], ga[8];
    #pragma unroll
    for (int t = 0; t < 8; ++t) {
        ka[t] = KVb[kvoff + (long)t * (D * D)];
        ga[t] = Gb[goff + (long)t * D];
    }
    float st = 0.f;
    for (int c0 = 0; c0 < NC; c0 += 8) {
        float kb[8], gb2[8];
        const bool more = (c0 + 8) < NC;
        #pragma unroll
        for (int t = 0; t < 8; ++t) {
            kb[t]  = more ? KVb[kvoff + (long)(c0 + 8 + t) * (D * D)] : 0.f;
            gb2[t] = more ? Gb[goff + (long)(c0 + 8 + t) * D] : 0.f;
        }
        #pragma unroll
        for (int t = 0; t < 8; ++t) {
            KVb[kvoff + (long)(c0 + t) * (D * D)] = st;
            st = ga[t] * st + ka[t];
        }
        #pragma unroll
        for (int t = 0; t < 8; ++t) { ka[t] = kb[t]; ga[t] = gb2[t]; }
    }
}

// ---------------- Kernel 3: MFMA per-chunk outputs (unchanged, verified) ------
__global__ __launch_bounds__(256)
void k3_mfma(const float* __restrict__ Qp, const float* __restrict__ Kp,
             const float* __restrict__ Vp, const float* __restrict__ Gp,
             const float* __restrict__ S0b, float* __restrict__ Op)
{
    __shared__ __align__(16) float  l_s[4][L][36];
    __shared__ __align__(16) ushort w_s[4][L][40];
    __shared__ __align__(16) ushort a_s[4][L][40];
    __shared__ float tot[4][D];

    const int tid = threadIdx.x;
    const int wv = tid >> 6;
    const int lane = tid & 63;
    const int half = lane >> 5;
    const int m = lane & 31;

    const int chunk = blockIdx.x * 4 + wv;
    const int bh = chunk >> 7;
    const int c = chunk & (NC - 1);
    const int b = bh >> 4;
    const int h = bh & (H - 1);
    const long base = ((long)b * S + (long)c * L) * RS + h * D;
    const float* S0c = S0b + (long)chunk * (D * D);

    const float* qrow = Qp + base + (long)m * RS + 8 * half;
    const float* krow = Kp + base + (long)m * RS + 8 * half;
    float4 qv0 = *(const float4*)(qrow);
    float4 qv1 = *(const float4*)(qrow + 4);
    float4 qv2 = *(const float4*)(qrow + 16);
    float4 qv3 = *(const float4*)(qrow + 20);
    float4 kv0 = *(const float4*)(krow);
    float4 kv1 = *(const float4*)(krow + 4);
    float4 kv2 = *(const float4*)(krow + 16);
    float4 kv3 = *(const float4*)(krow + 20);
    short8v qa0, qa1, ka0, ka1;
    {
        float qf[16] = {qv0.x,qv0.y,qv0.z,qv0.w, qv1.x,qv1.y,qv1.z,qv1.w,
                        qv2.x,qv2.y,qv2.z,qv2.w, qv3.x,qv3.y,qv3.z,qv3.w};
        float kf[16] = {kv0.x,kv0.y,kv0.z,kv0.w, kv1.x,kv1.y,kv1.z,kv1.w,
                        kv2.x,kv2.y,kv2.z,kv2.w, kv3.x,kv3.y,kv3.z,kv3.w};
        #pragma unroll
        for (int e = 0; e < 8; ++e) {
            qa0[e] = f2bf(qf[e]);     qa1[e] = f2bf(qf[8 + e]);
            ka0[e] = f2bf(kf[e]);     ka1[e] = f2bf(kf[8 + e]);
        }
    }

    float cum[16];
    {
        const float* gcol = Gp + base + (long)(half * 16) * RS + m;
        float run = 0.f;
        #pragma unroll
        for (int t = 0; t < 16; ++t) {
            run += flog2(fmaxf(gcol[(long)t * RS], GEPS));
            cum[t] = run;
        }
    }
    if (half == 0) tot[wv][m] = cum[15];
    __syncthreads();                                 // b1
    {
        const float basel = (half == 1) ? tot[wv][m] : 0.f;
        #pragma unroll
        for (int t = 0; t < 16; ++t) cum[t] += basel;
    }
    const float e_a = cum[7], e_b = cum[15];

    {
        const float* vcol = Vp + base + (long)(half * 16) * RS + m;
        #pragma unroll
        for (int t = 0; t < 16; ++t) {
            const int r = half * 16 + t;
            const float e = (t < 8) ? e_a : e_b;
            const float w = vcol[(long)t * RS] * fexp2(e - cum[t]);
            w_s[wv][r][m] = (ushort)f2bf(w);
            l_s[wv][r][m] = cum[t];
        }
    }
    __syncthreads();                                 // b2

    f32x16 acc;
    #pragma unroll
    for (int e = 0; e < 16; ++e) acc[e] = 0.f;
    acc = __builtin_amdgcn_mfma_f32_32x32x16_bf16(qa0, ka0, acc, 0, 0, 0);
    acc = __builtin_amdgcn_mfma_f32_32x32x16_bf16(qa1, ka1, acc, 0, 0, 0);
    #pragma unroll
    for (int reg = 0; reg < 16; ++reg) {
        const int irow = (reg & 3) + 8 * (reg >> 2) + 4 * half;
        const float av = (m <= irow) ? acc[reg] : 0.f;
        a_s[wv][irow][m] = (ushort)f2bf(av);
    }
    __syncthreads();                                 // b3

    float li[16];
    #pragma unroll
    for (int reg = 0; reg < 16; ++reg)
        li[reg] = l_s[wv][(reg & 3) + 8 * (reg >> 2) + 4 * half][m];
    float es4[4];
    #pragma unroll
    for (int s = 0; s < 4; ++s) es4[s] = l_s[wv][8 * s + 7][m];

    f32x16 sacc;
    #pragma unroll
    for (int e = 0; e < 16; ++e) sacc[e] = 0.f;
    {
        short8v sf0, sf1;
        #pragma unroll
        for (int e = 0; e < 8; ++e) {
            sf0[e] = f2bf(S0c[(8 * half + e) * D + m]);
            sf1[e] = f2bf(S0c[(16 + 8 * half + e) * D + m]);
        }
        sacc = __builtin_amdgcn_mfma_f32_32x32x16_bf16(qa0, sf0, sacc, 0, 0, 0);
        sacc = __builtin_amdgcn_mfma_f32_32x32x16_bf16(qa1, sf1, sacc, 0, 0, 0);
    }
    f32x16 out;
    #pragma unroll
    for (int reg = 0; reg < 16; ++reg) out[reg] = fexp2(li[reg]) * sacc[reg];

    #pragma unroll
    for (int ks = 0; ks < 2; ++ks) {
        const short8v af = *(const short8v*)&a_s[wv][m][16 * ks + 8 * half];
        short8v wf;
        #pragma unroll
        for (int e = 0; e < 8; ++e)
            wf[e] = (short)w_s[wv][16 * ks + 8 * half + e][m];
        #pragma unroll
        for (int par = 0; par < 2; ++par) {
            const int s = 2 * ks + par;
            short8v am;
            #pragma unroll
            for (int e = 0; e < 8; ++e) am[e] = (half == par) ? af[e] : (short)0;
            f32x16 p;
            #pragma unroll
            for (int e = 0; e < 16; ++e) p[e] = 0.f;
            p = __builtin_amdgcn_mfma_f32_32x32x16_bf16(am, wf, p, 0, 0, 0);
            #pragma unroll
            for (int reg = 0; reg < 16; ++reg)
                out[reg] += fexp2(fminf(li[reg] - es4[s], 120.f)) * p[reg];
        }
    }

    #pragma unroll
    for (int reg = 0; reg < 16; ++reg) {
        const int irow = (reg & 3) + 8 * (reg >> 2) + 4 * half;
        Op[base + (long)irow * RS + m] = out[reg];
    }
}

} // namespace

extern "C" void kernel_launch(void* const* d_in, const int* in_sizes, int n_in,
                              void* d_out, int out_size, void* d_ws, size_t ws_size,
                              hipStream_t stream)
{
    const float* q = (const float*)d_in[0];
    const float* k = (const float*)d_in[1];
    const float* v = (const float*)d_in[2];
    const float* g = (const float*)d_in[3];
    float* out = (float*)d_out;

    float* KVb = (float*)d_ws;                       // [NBH][NC][D][D]  (33.55 MB)
    float* Gb = KVb + (long)NBH * NC * D * D;        // [NBH][NC][D]     (1.05 MB)

    dim3 blk(256);
    k1_stage<<<dim3(NBH * NC), blk, 0, stream>>>(k, v, g, KVb, Gb);
    k2_scan<<<dim3(NBH * 4), blk, 0, stream>>>(KVb, Gb);
    k3_mfma<<<dim3(NBH * NC / 4), blk, 0, stream>>>(q, k, v, g, KVb, out);
}

// Round 16
// 66.256 us; speedup vs baseline: 4.5692x; 1.1133x over previous
//
#include <hip/hip_runtime.h>

namespace {

constexpr int B = 4, S = 4096, H = 16, D = 32;
constexpr int L = 32;             // chunk length
constexpr int NC = S / L;         // 128 chunks per sequence
constexpr int NBH = B * H;        // 64
constexpr int RS = H * D;         // 512 floats between consecutive time steps
constexpr int NSEG = 8;           // segments per (b,h)
constexpr int SEGC = NC / NSEG;   // 16 chunks per segment
constexpr float GEPS = 1.52587890625e-05f;  // 2^-16 per-step decay clamp

// Lore (rounds 6-15, measured):
//  - launch_bounds(256,w) caps VGPR ~256/w; cap < live set => GB-scale spill.
//  - Scalar j-loops over LDS tiles are LDS-instruction bound -> MFMA.
//  - COLD scalar column loads (stride RS) are latency death (r13); row float4
//    + LDS staging for cold data, column loads OK when L3-warm (r12 k3).
//  - r15 bug: the state-update KVc MFMA needs TOTAL-scaled W (v*2^{total-l}),
//    not the P-matmul's sub-block-scaled W (v*2^{e_s-l}). Rescale fragments by
//    2^{es4[3]-es4[sub-block]} (<=1) before the KVc MFMA.
//  - MFMA operand convention (HW-verified r12, absmax 0.5):
//    A-op: row = lane&31, k = 8*(lane>>5)+e (+16 for 2nd MFMA)
//    B-op: col = lane&31, same k
//    C/D : col = lane&31, row = (reg&3)+8*(reg>>2)+4*(lane>>5)

typedef __attribute__((ext_vector_type(8)))  short short8v;   // 8 bf16 = 4 VGPR
typedef __attribute__((ext_vector_type(16))) float f32x16;    // 16 f32 acc

__device__ __forceinline__ float flog2(float x) { return __builtin_amdgcn_logf(x); }
__device__ __forceinline__ float fexp2(float x) { return __builtin_amdgcn_exp2f(x); }
__device__ __forceinline__ unsigned f2bfu(float f) {          // fp32 -> bf16 (RNE)
    unsigned u = __float_as_uint(f);
    return (u + 0x7FFFu + ((u >> 16) & 1u)) >> 16;
}
__device__ __forceinline__ short f2bf(float f) { return (short)f2bfu(f); }
__device__ __forceinline__ float bf2f(short s) {              // bf16 -> fp32
    return __uint_as_float(((unsigned)(ushort)s) << 16);
}

// ---------------- Kernel A: segment summaries -------------------------------
// One block per (bh, seg); 16 chunks sequential. Per chunk: r14-k1 body
// (row staging + LDS column scan + W bf16 + wave0 2xMFMA), state kept in LDS:
//   S = 2^{total_c} o S + KVc,   ltot += total_c
// Output: SegKV[blk][32][32] f32, SegLT[blk][32] (log2 of segment gate prod).
__global__ __launch_bounds__(256)
void kA_segsum(const float* __restrict__ Kp, const float* __restrict__ Vp,
               const float* __restrict__ Gp, float* __restrict__ SegKV,
               float* __restrict__ SegLT)
{
    __shared__ __align__(16) float  k_s[L][36];
    __shared__ __align__(16) float  lg[L][36];
    __shared__ __align__(16) ushort w_s[L][40];
    __shared__ float sub[8][D];
    __shared__ float totr[D];
    __shared__ float S_lds[D][33];
    __shared__ float ltot[D];

    const int blk = blockIdx.x;              // bh*NSEG + seg
    const int bh = blk >> 3, seg = blk & 7;
    const int b = bh >> 4, h = bh & (H - 1);

    const int tid = threadIdx.x;
    const int i = tid >> 3;                  // row 0..31
    const int u = (tid & 7) * 4;             // col quad
    const int m = tid & 31, t = tid >> 5;    // scan mapping
    const int r0 = t * 4;

    #pragma unroll
    for (int z = 0; z < 4; ++z) S_lds[i][u + z] = 0.f;
    if (tid < D) ltot[tid] = 0.f;

    for (int cc = 0; cc < SEGC; ++cc) {
        const int c = seg * SEGC + cc;
        const long base = ((long)b * S + (long)c * L) * RS + h * D;
        const long roff = base + (long)i * RS + u;
        float4 k4 = *(const float4*)(Kp + roff);
        float4 v4 = *(const float4*)(Vp + roff);
        float4 g4 = *(const float4*)(Gp + roff);
        __syncthreads();                     // prev chunk fully consumed (+init)
        *(float4*)&k_s[i][u] = k4;
        float4 lv;
        lv.x = flog2(fmaxf(g4.x, GEPS));
        lv.y = flog2(fmaxf(g4.y, GEPS));
        lv.z = flog2(fmaxf(g4.z, GEPS));
        lv.w = flog2(fmaxf(g4.w, GEPS));
        *(float4*)&lg[i][u] = lv;
        __syncthreads();                     // b1

        float c0 = lg[r0 + 0][m];
        float c1 = c0 + lg[r0 + 1][m];
        float c2 = c1 + lg[r0 + 2][m];
        float c3 = c2 + lg[r0 + 3][m];
        sub[t][m] = c3;
        __syncthreads();                     // b2

        {
            float sb[8];
            float total = 0.f;
            #pragma unroll
            for (int tt = 0; tt < 8; ++tt) { sb[tt] = sub[tt][m]; total += sb[tt]; }
            float base_l = 0.f;
            #pragma unroll
            for (int tt = 0; tt < 8; ++tt) { if (tt < t) base_l += sb[tt]; }
            lg[r0 + 0][m] = base_l + c0;
            lg[r0 + 1][m] = base_l + c1;
            lg[r0 + 2][m] = base_l + c2;
            lg[r0 + 3][m] = base_l + c3;
            if (t == 0) { totr[m] = total; ltot[m] += total; }
        }
        __syncthreads();                     // b3

        {
            float4 l4 = *(float4*)&lg[i][u];
            float4 t4 = *(float4*)&totr[u];
            unsigned p0 = f2bfu(v4.x * fexp2(t4.x - l4.x))
                        | (f2bfu(v4.y * fexp2(t4.y - l4.y)) << 16);
            unsigned p1 = f2bfu(v4.z * fexp2(t4.z - l4.z))
                        | (f2bfu(v4.w * fexp2(t4.w - l4.w)) << 16);
            uint2 pp; pp.x = p0; pp.y = p1;
            *(uint2*)&w_s[i][u] = pp;
        }
        __syncthreads();                     // b4

        if (tid < 64) {                      // wave 0: 2 MFMAs + state update
            const int half = tid >> 5;
            const int mm = tid & 31;
            short8v ka0, ka1, wf0, wf1;
            #pragma unroll
            for (int e = 0; e < 8; ++e) {
                ka0[e] = f2bf(k_s[8 * half + e][mm]);
                ka1[e] = f2bf(k_s[16 + 8 * half + e][mm]);
                wf0[e] = (short)w_s[8 * half + e][mm];
                wf1[e] = (short)w_s[16 + 8 * half + e][mm];
            }
            f32x16 acc;
            #pragma unroll
            for (int e = 0; e < 16; ++e) acc[e] = 0.f;
            acc = __builtin_amdgcn_mfma_f32_32x32x16_bf16(ka0, wf0, acc, 0, 0, 0);
            acc = __builtin_amdgcn_mfma_f32_32x32x16_bf16(ka1, wf1, acc, 0, 0, 0);
            const float gs = fexp2(totr[mm]);
            #pragma unroll
            for (int reg = 0; reg < 16; ++reg) {
                const int r = (reg & 3) + 8 * (reg >> 2) + 4 * half;
                S_lds[r][mm] = gs * S_lds[r][mm] + acc[reg];
            }
        }
    }
    __syncthreads();

    {
        float4 sv;
        sv.x = S_lds[i][u + 0]; sv.y = S_lds[i][u + 1];
        sv.z = S_lds[i][u + 2]; sv.w = S_lds[i][u + 3];
        *(float4*)(SegKV + (long)blk * (D * D) + i * D + u) = sv;
    }
    if (tid < D) SegLT[blk * D + tid] = ltot[tid];
}

// ---------------- Kernel B: compose start + outputs -------------------------
// One block per (bh, seg). Compose S from prior segment summaries (log space),
// then 4 groups x 4 chunks (wave per chunk, r12-k3 body) with a 4-slot barrier
// relay for the state-dependent QS0-read + state-update.
__global__ __launch_bounds__(256)
void kB_out(const float* __restrict__ Qp, const float* __restrict__ Kp,
            const float* __restrict__ Vp, const float* __restrict__ Gp,
            const float* __restrict__ SegKV, const float* __restrict__ SegLT,
            float* __restrict__ Op)
{
    __shared__ __align__(16) float  l_s[4][L][36];
    __shared__ __align__(16) ushort w_s[4][L][40];
    __shared__ __align__(16) ushort a_s[4][L][40];
    __shared__ float tot[4][D];
    __shared__ float S_lds[D][33];
    __shared__ float lt8[NSEG][D];

    const int blk = blockIdx.x;
    const int bh = blk >> 3, seg = blk & 7;
    const int b = bh >> 4, h = bh & (H - 1);

    const int tid = threadIdx.x;
    const int wv = tid >> 6;
    const int lane = tid & 63;
    const int half = lane >> 5;
    const int m = lane & 31;

    // stage SegLT for this bh
    {
        const int s = tid >> 5, mm = tid & 31;
        lt8[s][mm] = SegLT[(bh * NSEG + s) * D + mm];
    }
    __syncthreads();

    // compose start state: S = sum_{sp<seg} SegKV[sp] * 2^{sum_{sp<s''<seg} lt}
    {
        const int d = tid >> 3;
        const int u4 = (tid & 7) * 4;
        float4 Sv = {0, 0, 0, 0};
        float r0 = 0.f, r1 = 0.f, r2 = 0.f, r3 = 0.f;
        for (int sp = seg - 1; sp >= 0; --sp) {
            float4 kv = *(const float4*)(SegKV + (long)(bh * NSEG + sp) * (D * D)
                                         + d * D + u4);
            Sv.x += kv.x * fexp2(r0); Sv.y += kv.y * fexp2(r1);
            Sv.z += kv.z * fexp2(r2); Sv.w += kv.w * fexp2(r3);
            r0 += lt8[sp][u4 + 0]; r1 += lt8[sp][u4 + 1];
            r2 += lt8[sp][u4 + 2]; r3 += lt8[sp][u4 + 3];
        }
        S_lds[d][u4 + 0] = Sv.x; S_lds[d][u4 + 1] = Sv.y;
        S_lds[d][u4 + 2] = Sv.z; S_lds[d][u4 + 3] = Sv.w;
    }
    __syncthreads();

    for (int grp = 0; grp < 4; ++grp) {
        const int c = seg * SEGC + grp * 4 + wv;
        const long base = ((long)b * S + (long)c * L) * RS + h * D;

        // ---- part 1 (wave-parallel, r12 body) ----
        const float* qrow = Qp + base + (long)m * RS + 8 * half;
        const float* krow = Kp + base + (long)m * RS + 8 * half;
        float4 qv0 = *(const float4*)(qrow);
        float4 qv1 = *(const float4*)(qrow + 4);
        float4 qv2 = *(const float4*)(qrow + 16);
        float4 qv3 = *(const float4*)(qrow + 20);
        float4 kv0 = *(const float4*)(krow);
        float4 kv1 = *(const float4*)(krow + 4);
        float4 kv2 = *(const float4*)(krow + 16);
        float4 kv3 = *(const float4*)(krow + 20);
        short8v qa0, qa1, kb0, kb1;
        {
            float qf[16] = {qv0.x,qv0.y,qv0.z,qv0.w, qv1.x,qv1.y,qv1.z,qv1.w,
                            qv2.x,qv2.y,qv2.z,qv2.w, qv3.x,qv3.y,qv3.z,qv3.w};
            float kf[16] = {kv0.x,kv0.y,kv0.z,kv0.w, kv1.x,kv1.y,kv1.z,kv1.w,
                            kv2.x,kv2.y,kv2.z,kv2.w, kv3.x,kv3.y,kv3.z,kv3.w};
            #pragma unroll
            for (int e = 0; e < 8; ++e) {
                qa0[e] = f2bf(qf[e]);     qa1[e] = f2bf(qf[8 + e]);
                kb0[e] = f2bf(kf[e]);     kb1[e] = f2bf(kf[8 + e]);
            }
        }

        float cum[16];
        {
            const float* gcol = Gp + base + (long)(half * 16) * RS + m;
            float run = 0.f;
            #pragma unroll
            for (int t = 0; t < 16; ++t) {
                run += flog2(fmaxf(gcol[(long)t * RS], GEPS));
                cum[t] = run;
            }
        }
        if (half == 0) tot[wv][m] = cum[15];
        __syncthreads();                           // g.b1
        {
            const float basel = (half == 1) ? tot[wv][m] : 0.f;
            #pragma unroll
            for (int t = 0; t < 16; ++t) cum[t] += basel;
        }
        const float e_a = cum[7], e_b = cum[15];

        {
            const float* vcol = Vp + base + (long)(half * 16) * RS + m;
            #pragma unroll
            for (int t = 0; t < 16; ++t) {
                const int r = half * 16 + t;
                const float e = (t < 8) ? e_a : e_b;
                const float w = vcol[(long)t * RS] * fexp2(e - cum[t]);
                w_s[wv][r][m] = (ushort)f2bf(w);
                l_s[wv][r][m] = cum[t];
            }
        }
        __syncthreads();                           // g.b2

        // Gram A = Q.K^T -> masked bf16 a_s
        f32x16 acc;
        #pragma unroll
        for (int e = 0; e < 16; ++e) acc[e] = 0.f;
        acc = __builtin_amdgcn_mfma_f32_32x32x16_bf16(qa0, kb0, acc, 0, 0, 0);
        acc = __builtin_amdgcn_mfma_f32_32x32x16_bf16(qa1, kb1, acc, 0, 0, 0);
        #pragma unroll
        for (int reg = 0; reg < 16; ++reg) {
            const int irow = (reg & 3) + 8 * (reg >> 2) + 4 * half;
            const float av = (m <= irow) ? acc[reg] : 0.f;
            a_s[wv][irow][m] = (ushort)f2bf(av);
        }

        float li[16];
        #pragma unroll
        for (int reg = 0; reg < 16; ++reg)
            li[reg] = l_s[wv][(reg & 3) + 8 * (reg >> 2) + 4 * half][m];
        float es4[4];
        #pragma unroll
        for (int s = 0; s < 4; ++s) es4[s] = l_s[wv][8 * s + 7][m];

        // W B-frags (sub-block-scaled; used by P MFMAs)
        short8v wfk0, wfk1;
        #pragma unroll
        for (int e = 0; e < 8; ++e) {
            wfk0[e] = (short)w_s[wv][8 * half + e][m];
            wfk1[e] = (short)w_s[wv][16 + 8 * half + e][m];
        }
        // r15 FIX: KVc needs TOTAL-scaled W: multiply by 2^{total - e_s(row)}.
        // MFMA1 rows 8*half+e -> sub-block = half; MFMA2 rows 16+8*half+e -> 2+half.
        const float fac0 = fexp2(es4[3] - es4[half]);       // <= 1
        const float fac1 = fexp2(es4[3] - es4[2 + half]);   // <= 1
        short8v wkv0, wkv1;
        #pragma unroll
        for (int e = 0; e < 8; ++e) {
            wkv0[e] = f2bf(bf2f(wfk0[e]) * fac0);
            wkv1[e] = f2bf(bf2f(wfk1[e]) * fac1);
        }
        // KVc = K^T . W_total  (K columns from global, L3-warm)
        f32x16 kvacc;
        #pragma unroll
        for (int e = 0; e < 16; ++e) kvacc[e] = 0.f;
        {
            const float* kcol = Kp + base + m;
            short8v kta0, kta1;
            #pragma unroll
            for (int e = 0; e < 8; ++e) {
                kta0[e] = f2bf(kcol[(long)(8 * half + e) * RS]);
                kta1[e] = f2bf(kcol[(long)(16 + 8 * half + e) * RS]);
            }
            kvacc = __builtin_amdgcn_mfma_f32_32x32x16_bf16(kta0, wkv0, kvacc, 0, 0, 0);
            kvacc = __builtin_amdgcn_mfma_f32_32x32x16_bf16(kta1, wkv1, kvacc, 0, 0, 0);
        }
        __syncthreads();                           // g.b3 (a_s ready)

        // ---- relay: chunk-ordered S0 read + state update ----
        short8v sf0, sf1;
        #pragma unroll
        for (int s = 0; s < 4; ++s) {
            __syncthreads();
            if (wv == s) {
                #pragma unroll
                for (int e = 0; e < 8; ++e) {
                    sf0[e] = f2bf(S_lds[8 * half + e][m]);
                    sf1[e] = f2bf(S_lds[16 + 8 * half + e][m]);
                }
                const float gs = fexp2(es4[3]);    // 2^{total_c}
                #pragma unroll
                for (int reg = 0; reg < 16; ++reg) {
                    const int r = (reg & 3) + 8 * (reg >> 2) + 4 * half;
                    S_lds[r][m] = gs * S_lds[r][m] + kvacc[reg];
                }
            }
        }
        __syncthreads();                           // relay done

        // ---- part 3: QS0 + P + epilogue (wave-parallel) ----
        f32x16 sacc;
        #pragma unroll
        for (int e = 0; e < 16; ++e) sacc[e] = 0.f;
        sacc = __builtin_amdgcn_mfma_f32_32x32x16_bf16(qa0, sf0, sacc, 0, 0, 0);
        sacc = __builtin_amdgcn_mfma_f32_32x32x16_bf16(qa1, sf1, sacc, 0, 0, 0);
        f32x16 out;
        #pragma unroll
        for (int reg = 0; reg < 16; ++reg) out[reg] = fexp2(li[reg]) * sacc[reg];

        #pragma unroll
        for (int ks = 0; ks < 2; ++ks) {
            const short8v af = *(const short8v*)&a_s[wv][m][16 * ks + 8 * half];
            const short8v wf = ks ? wfk1 : wfk0;
            #pragma unroll
            for (int par = 0; par < 2; ++par) {
                const int s = 2 * ks + par;
                short8v am;
                #pragma unroll
                for (int e = 0; e < 8; ++e) am[e] = (half == par) ? af[e] : (short)0;
                f32x16 p;
                #pragma unroll
                for (int e = 0; e < 16; ++e) p[e] = 0.f;
                p = __builtin_amdgcn_mfma_f32_32x32x16_bf16(am, wf, p, 0, 0, 0);
                #pragma unroll
                for (int reg = 0; reg < 16; ++reg)
                    out[reg] += fexp2(fminf(li[reg] - es4[s], 120.f)) * p[reg];
            }
        }

        #pragma unroll
        for (int reg = 0; reg < 16; ++reg) {
            const int irow = (reg & 3) + 8 * (reg >> 2) + 4 * half;
            Op[base + (long)irow * RS + m] = out[reg];
        }
    }
}

} // namespace

extern "C" void kernel_launch(void* const* d_in, const int* in_sizes, int n_in,
                              void* d_out, int out_size, void* d_ws, size_t ws_size,
                              hipStream_t stream)
{
    const float* q = (const float*)d_in[0];
    const float* k = (const float*)d_in[1];
    const float* v = (const float*)d_in[2];
    const float* g = (const float*)d_in[3];
    float* out = (float*)d_out;

    float* SegKV = (float*)d_ws;                        // [512][32][32] f32 (2 MB)
    float* SegLT = SegKV + (long)NBH * NSEG * D * D;    // [512][32]      (64 KB)

    dim3 blk(256);
    kA_segsum<<<dim3(NBH * NSEG), blk, 0, stream>>>(k, v, g, SegKV, SegLT);
    kB_out<<<dim3(NBH * NSEG), blk, 0, stream>>>(q, k, v, g, SegKV, SegLT, out);
}

// Round 17
// 64.973 us; speedup vs baseline: 4.6594x; 1.0197x over previous
//
#include <hip/hip_runtime.h>

namespace {

constexpr int B = 4, S = 4096, H = 16, D = 32;
constexpr int L = 32;             // chunk length
constexpr int NC = S / L;         // 128 chunks per sequence
constexpr int NBH = B * H;        // 64
constexpr int RS = H * D;         // 512 floats between consecutive time steps
constexpr int NSEG = 16;          // segments per (b,h)
constexpr int SEGC = NC / NSEG;   // 8 chunks per segment
constexpr float GEPS = 1.52587890625e-05f;  // 2^-16 per-step decay clamp

// Lore (rounds 6-16, measured):
//  - launch_bounds(256,w) caps VGPR ~256/w; cap < live set => GB-scale spill.
//  - Scalar j-loops over LDS tiles are LDS-instruction bound -> MFMA.
//  - COLD scalar column loads (stride RS) are latency death (r13); row float4
//    + LDS staging for cold data, column loads OK when L3-warm (r12 k3).
//  - KVc state-update MFMA needs TOTAL-scaled W; rescale P-frags by
//    2^{es4[3]-es4[sub]} (r15 bug -> r16 fix, verified absmax 0.5).
//  - r16: kB latency-bound at 2 blocks/CU (grid 512) + 44.7KB LDS.
//    This round: NSEG 8->16 (grid 1024 = 4/CU) + LDS 39.6KB (4/CU cap).
//  - MFMA operand convention (HW-verified r12, absmax 0.5):
//    A-op: row = lane&31, k = 8*(lane>>5)+e (+16 for 2nd MFMA)
//    B-op: col = lane&31, same k
//    C/D : col = lane&31, row = (reg&3)+8*(reg>>2)+4*(lane>>5)

typedef __attribute__((ext_vector_type(8)))  short short8v;   // 8 bf16 = 4 VGPR
typedef __attribute__((ext_vector_type(16))) float f32x16;    // 16 f32 acc

__device__ __forceinline__ float flog2(float x) { return __builtin_amdgcn_logf(x); }
__device__ __forceinline__ float fexp2(float x) { return __builtin_amdgcn_exp2f(x); }
__device__ __forceinline__ unsigned f2bfu(float f) {          // fp32 -> bf16 (RNE)
    unsigned u = __float_as_uint(f);
    return (u + 0x7FFFu + ((u >> 16) & 1u)) >> 16;
}
__device__ __forceinline__ short f2bf(float f) { return (short)f2bfu(f); }
__device__ __forceinline__ float bf2f(short s) {              // bf16 -> fp32
    return __uint_as_float(((unsigned)(ushort)s) << 16);
}

// ---------------- Kernel A: segment summaries -------------------------------
// One block per (bh, seg); SEGC chunks sequential. Per chunk: row staging +
// LDS column scan + W bf16 + wave0 2xMFMA; state in LDS:
//   S = 2^{total_c} o S + KVc,   ltot += total_c
// Output: SegKV[blk][32][32] f32, SegLT[blk][32].
__global__ __launch_bounds__(256)
void kA_segsum(const float* __restrict__ Kp, const float* __restrict__ Vp,
               const float* __restrict__ Gp, float* __restrict__ SegKV,
               float* __restrict__ SegLT)
{
    __shared__ __align__(16) float  k_s[L][36];
    __shared__ __align__(16) float  lg[L][36];
    __shared__ __align__(16) ushort w_s[L][40];
    __shared__ float sub[8][D];
    __shared__ float totr[D];
    __shared__ float S_lds[D][33];
    __shared__ float ltot[D];

    const int blk = blockIdx.x;              // bh*NSEG + seg
    const int bh = blk / NSEG, seg = blk % NSEG;
    const int b = bh >> 4, h = bh & (H - 1);

    const int tid = threadIdx.x;
    const int i = tid >> 3;                  // row 0..31
    const int u = (tid & 7) * 4;             // col quad
    const int m = tid & 31, t = tid >> 5;    // scan mapping
    const int r0 = t * 4;

    #pragma unroll
    for (int z = 0; z < 4; ++z) S_lds[i][u + z] = 0.f;
    if (tid < D) ltot[tid] = 0.f;

    for (int cc = 0; cc < SEGC; ++cc) {
        const int c = seg * SEGC + cc;
        const long base = ((long)b * S + (long)c * L) * RS + h * D;
        const long roff = base + (long)i * RS + u;
        float4 k4 = *(const float4*)(Kp + roff);
        float4 v4 = *(const float4*)(Vp + roff);
        float4 g4 = *(const float4*)(Gp + roff);
        __syncthreads();                     // prev chunk fully consumed (+init)
        *(float4*)&k_s[i][u] = k4;
        float4 lv;
        lv.x = flog2(fmaxf(g4.x, GEPS));
        lv.y = flog2(fmaxf(g4.y, GEPS));
        lv.z = flog2(fmaxf(g4.z, GEPS));
        lv.w = flog2(fmaxf(g4.w, GEPS));
        *(float4*)&lg[i][u] = lv;
        __syncthreads();                     // b1

        float c0 = lg[r0 + 0][m];
        float c1 = c0 + lg[r0 + 1][m];
        float c2 = c1 + lg[r0 + 2][m];
        float c3 = c2 + lg[r0 + 3][m];
        sub[t][m] = c3;
        __syncthreads();                     // b2

        {
            float sb[8];
            float total = 0.f;
            #pragma unroll
            for (int tt = 0; tt < 8; ++tt) { sb[tt] = sub[tt][m]; total += sb[tt]; }
            float base_l = 0.f;
            #pragma unroll
            for (int tt = 0; tt < 8; ++tt) { if (tt < t) base_l += sb[tt]; }
            lg[r0 + 0][m] = base_l + c0;
            lg[r0 + 1][m] = base_l + c1;
            lg[r0 + 2][m] = base_l + c2;
            lg[r0 + 3][m] = base_l + c3;
            if (t == 0) { totr[m] = total; ltot[m] += total; }
        }
        __syncthreads();                     // b3

        {
            float4 l4 = *(float4*)&lg[i][u];
            float4 t4 = *(float4*)&totr[u];
            unsigned p0 = f2bfu(v4.x * fexp2(t4.x - l4.x))
                        | (f2bfu(v4.y * fexp2(t4.y - l4.y)) << 16);
            unsigned p1 = f2bfu(v4.z * fexp2(t4.z - l4.z))
                        | (f2bfu(v4.w * fexp2(t4.w - l4.w)) << 16);
            uint2 pp; pp.x = p0; pp.y = p1;
            *(uint2*)&w_s[i][u] = pp;
        }
        __syncthreads();                     // b4

        if (tid < 64) {                      // wave 0: 2 MFMAs + state update
            const int half = tid >> 5;
            const int mm = tid & 31;
            short8v ka0, ka1, wf0, wf1;
            #pragma unroll
            for (int e = 0; e < 8; ++e) {
                ka0[e] = f2bf(k_s[8 * half + e][mm]);
                ka1[e] = f2bf(k_s[16 + 8 * half + e][mm]);
                wf0[e] = (short)w_s[8 * half + e][mm];
                wf1[e] = (short)w_s[16 + 8 * half + e][mm];
            }
            f32x16 acc;
            #pragma unroll
            for (int e = 0; e < 16; ++e) acc[e] = 0.f;
            acc = __builtin_amdgcn_mfma_f32_32x32x16_bf16(ka0, wf0, acc, 0, 0, 0);
            acc = __builtin_amdgcn_mfma_f32_32x32x16_bf16(ka1, wf1, acc, 0, 0, 0);
            const float gs = fexp2(totr[mm]);
            #pragma unroll
            for (int reg = 0; reg < 16; ++reg) {
                const int r = (reg & 3) + 8 * (reg >> 2) + 4 * half;
                S_lds[r][mm] = gs * S_lds[r][mm] + acc[reg];
            }
        }
    }
    __syncthreads();

    {
        float4 sv;
        sv.x = S_lds[i][u + 0]; sv.y = S_lds[i][u + 1];
        sv.z = S_lds[i][u + 2]; sv.w = S_lds[i][u + 3];
        *(float4*)(SegKV + (long)blk * (D * D) + i * D + u) = sv;
    }
    if (tid < D) SegLT[blk * D + tid] = ltot[tid];
}

// ---------------- Kernel B: compose start + outputs -------------------------
// One block per (bh, seg). Compose S from prior segment summaries (log space),
// then SEGC/4 groups x 4 chunks (wave per chunk, r12-k3 body) with a 4-slot
// barrier relay for the state-dependent QS0-read + state-update.
// LDS 39.6 KB -> 4 blocks/CU (grid 1024 = 4/CU).
__global__ __launch_bounds__(256)
void kB_out(const float* __restrict__ Qp, const float* __restrict__ Kp,
            const float* __restrict__ Vp, const float* __restrict__ Gp,
            const float* __restrict__ SegKV, const float* __restrict__ SegLT,
            float* __restrict__ Op)
{
    __shared__ __align__(16) float  l_s[4][L][32];   // unpadded: kB does only
                                                     // row-broadcast/col reads
    __shared__ __align__(16) ushort w_s[4][L][36];   // scalar reads only
    __shared__ union AU {                            // lt8 dead before a_s live
        ushort a_s[4][L][40];                        // b128 reads need 80B rows
        float  lt8[NSEG][D];
    } au;
    __shared__ float tot[4][D];
    __shared__ float S_lds[D][33];

    const int blk = blockIdx.x;
    const int bh = blk / NSEG, seg = blk % NSEG;
    const int b = bh >> 4, h = bh & (H - 1);

    const int tid = threadIdx.x;
    const int wv = tid >> 6;
    const int lane = tid & 63;
    const int half = lane >> 5;
    const int m = lane & 31;

    // stage SegLT for this bh (NSEG*D = 512 floats)
    for (int z = tid; z < NSEG * D; z += 256)
        au.lt8[z >> 5][z & 31] = SegLT[bh * NSEG * D + z];
    __syncthreads();

    // compose start state: S = sum_{sp<seg} SegKV[sp] * 2^{sum_{sp<s''<seg} lt}
    {
        const int d = tid >> 3;
        const int u4 = (tid & 7) * 4;
        float4 Sv = {0, 0, 0, 0};
        float r0 = 0.f, r1 = 0.f, r2 = 0.f, r3 = 0.f;
        for (int sp = seg - 1; sp >= 0; --sp) {
            float4 kv = *(const float4*)(SegKV + (long)(bh * NSEG + sp) * (D * D)
                                         + d * D + u4);
            Sv.x += kv.x * fexp2(r0); Sv.y += kv.y * fexp2(r1);
            Sv.z += kv.z * fexp2(r2); Sv.w += kv.w * fexp2(r3);
            r0 += au.lt8[sp][u4 + 0]; r1 += au.lt8[sp][u4 + 1];
            r2 += au.lt8[sp][u4 + 2]; r3 += au.lt8[sp][u4 + 3];
        }
        S_lds[d][u4 + 0] = Sv.x; S_lds[d][u4 + 1] = Sv.y;
        S_lds[d][u4 + 2] = Sv.z; S_lds[d][u4 + 3] = Sv.w;
    }
    __syncthreads();    // lt8 dead from here; a_s slot free

    for (int grp = 0; grp < SEGC / 4; ++grp) {
        const int c = seg * SEGC + grp * 4 + wv;
        const long base = ((long)b * S + (long)c * L) * RS + h * D;

        // ---- part 1 (wave-parallel, r12 body) ----
        const float* qrow = Qp + base + (long)m * RS + 8 * half;
        const float* krow = Kp + base + (long)m * RS + 8 * half;
        float4 qv0 = *(const float4*)(qrow);
        float4 qv1 = *(const float4*)(qrow + 4);
        float4 qv2 = *(const float4*)(qrow + 16);
        float4 qv3 = *(const float4*)(qrow + 20);
        float4 kv0 = *(const float4*)(krow);
        float4 kv1 = *(const float4*)(krow + 4);
        float4 kv2 = *(const float4*)(krow + 16);
        float4 kv3 = *(const float4*)(krow + 20);
        short8v qa0, qa1, kb0, kb1;
        {
            float qf[16] = {qv0.x,qv0.y,qv0.z,qv0.w, qv1.x,qv1.y,qv1.z,qv1.w,
                            qv2.x,qv2.y,qv2.z,qv2.w, qv3.x,qv3.y,qv3.z,qv3.w};
            float kf[16] = {kv0.x,kv0.y,kv0.z,kv0.w, kv1.x,kv1.y,kv1.z,kv1.w,
                            kv2.x,kv2.y,kv2.z,kv2.w, kv3.x,kv3.y,kv3.z,kv3.w};
            #pragma unroll
            for (int e = 0; e < 8; ++e) {
                qa0[e] = f2bf(qf[e]);     qa1[e] = f2bf(qf[8 + e]);
                kb0[e] = f2bf(kf[e]);     kb1[e] = f2bf(kf[8 + e]);
            }
        }

        float cum[16];
        {
            const float* gcol = Gp + base + (long)(half * 16) * RS + m;
            float run = 0.f;
            #pragma unroll
            for (int t = 0; t < 16; ++t) {
                run += flog2(fmaxf(gcol[(long)t * RS], GEPS));
                cum[t] = run;
            }
        }
        if (half == 0) tot[wv][m] = cum[15];
        __syncthreads();                           // g.b1
        {
            const float basel = (half == 1) ? tot[wv][m] : 0.f;
            #pragma unroll
            for (int t = 0; t < 16; ++t) cum[t] += basel;
        }
        const float e_a = cum[7], e_b = cum[15];

        {
            const float* vcol = Vp + base + (long)(half * 16) * RS + m;
            #pragma unroll
            for (int t = 0; t < 16; ++t) {
                const int r = half * 16 + t;
                const float e = (t < 8) ? e_a : e_b;
                const float w = vcol[(long)t * RS] * fexp2(e - cum[t]);
                w_s[wv][r][m] = (ushort)f2bf(w);
                l_s[wv][r][m] = cum[t];
            }
        }
        __syncthreads();                           // g.b2

        // Gram A = Q.K^T -> masked bf16 a_s
        f32x16 acc;
        #pragma unroll
        for (int e = 0; e < 16; ++e) acc[e] = 0.f;
        acc = __builtin_amdgcn_mfma_f32_32x32x16_bf16(qa0, kb0, acc, 0, 0, 0);
        acc = __builtin_amdgcn_mfma_f32_32x32x16_bf16(qa1, kb1, acc, 0, 0, 0);
        #pragma unroll
        for (int reg = 0; reg < 16; ++reg) {
            const int irow = (reg & 3) + 8 * (reg >> 2) + 4 * half;
            const float av = (m <= irow) ? acc[reg] : 0.f;
            au.a_s[wv][irow][m] = (ushort)f2bf(av);
        }

        float li[16];
        #pragma unroll
        for (int reg = 0; reg < 16; ++reg)
            li[reg] = l_s[wv][(reg & 3) + 8 * (reg >> 2) + 4 * half][m];
        float es4[4];
        #pragma unroll
        for (int s = 0; s < 4; ++s) es4[s] = l_s[wv][8 * s + 7][m];

        // W B-frags (sub-block-scaled; used by P MFMAs)
        short8v wfk0, wfk1;
        #pragma unroll
        for (int e = 0; e < 8; ++e) {
            wfk0[e] = (short)w_s[wv][8 * half + e][m];
            wfk1[e] = (short)w_s[wv][16 + 8 * half + e][m];
        }
        // KVc needs TOTAL-scaled W: x 2^{total - e_s(row)} (r16 fix, verified)
        const float fac0 = fexp2(es4[3] - es4[half]);       // <= 1
        const float fac1 = fexp2(es4[3] - es4[2 + half]);   // <= 1
        short8v wkv0, wkv1;
        #pragma unroll
        for (int e = 0; e < 8; ++e) {
            wkv0[e] = f2bf(bf2f(wfk0[e]) * fac0);
            wkv1[e] = f2bf(bf2f(wfk1[e]) * fac1);
        }
        // KVc = K^T . W_total  (K columns from global, L3-warm)
        f32x16 kvacc;
        #pragma unroll
        for (int e = 0; e < 16; ++e) kvacc[e] = 0.f;
        {
            const float* kcol = Kp + base + m;
            short8v kta0, kta1;
            #pragma unroll
            for (int e = 0; e < 8; ++e) {
                kta0[e] = f2bf(kcol[(long)(8 * half + e) * RS]);
                kta1[e] = f2bf(kcol[(long)(16 + 8 * half + e) * RS]);
            }
            kvacc = __builtin_amdgcn_mfma_f32_32x32x16_bf16(kta0, wkv0, kvacc, 0, 0, 0);
            kvacc = __builtin_amdgcn_mfma_f32_32x32x16_bf16(kta1, wkv1, kvacc, 0, 0, 0);
        }
        __syncthreads();                           // g.b3 (a_s ready)

        // ---- relay: chunk-ordered S0 read + state update ----
        short8v sf0, sf1;
        #pragma unroll
        for (int s = 0; s < 4; ++s) {
            __syncthreads();
            if (wv == s) {
                #pragma unroll
                for (int e = 0; e < 8; ++e) {
                    sf0[e] = f2bf(S_lds[8 * half + e][m]);
                    sf1[e] = f2bf(S_lds[16 + 8 * half + e][m]);
                }
                const float gs = fexp2(es4[3]);    // 2^{total_c}
                #pragma unroll
                for (int reg = 0; reg < 16; ++reg) {
                    const int r = (reg & 3) + 8 * (reg >> 2) + 4 * half;
                    S_lds[r][m] = gs * S_lds[r][m] + kvacc[reg];
                }
            }
        }
        __syncthreads();                           // relay done

        // ---- part 3: QS0 + P + epilogue (wave-parallel) ----
        f32x16 sacc;
        #pragma unroll
        for (int e = 0; e < 16; ++e) sacc[e] = 0.f;
        sacc = __builtin_amdgcn_mfma_f32_32x32x16_bf16(qa0, sf0, sacc, 0, 0, 0);
        sacc = __builtin_amdgcn_mfma_f32_32x32x16_bf16(qa1, sf1, sacc, 0, 0, 0);
        f32x16 out;
        #pragma unroll
        for (int reg = 0; reg < 16; ++reg) out[reg] = fexp2(li[reg]) * sacc[reg];

        #pragma unroll
        for (int ks = 0; ks < 2; ++ks) {
            const short8v af = *(const short8v*)&au.a_s[wv][m][16 * ks + 8 * half];
            const short8v wf = ks ? wfk1 : wfk0;
            #pragma unroll
            for (int par = 0; par < 2; ++par) {
                const int s = 2 * ks + par;
                short8v am;
                #pragma unroll
                for (int e = 0; e < 8; ++e) am[e] = (half == par) ? af[e] : (short)0;
                f32x16 p;
                #pragma unroll
                for (int e = 0; e < 16; ++e) p[e] = 0.f;
                p = __builtin_amdgcn_mfma_f32_32x32x16_bf16(am, wf, p, 0, 0, 0);
                #pragma unroll
                for (int reg = 0; reg < 16; ++reg)
                    out[reg] += fexp2(fminf(li[reg] - es4[s], 120.f)) * p[reg];
            }
        }

        #pragma unroll
        for (int reg = 0; reg < 16; ++reg) {
            const int irow = (reg & 3) + 8 * (reg >> 2) + 4 * half;
            Op[base + (long)irow * RS + m] = out[reg];
        }
    }
}

} // namespace

extern "C" void kernel_launch(void* const* d_in, const int* in_sizes, int n_in,
                              void* d_out, int out_size, void* d_ws, size_t ws_size,
                              hipStream_t stream)
{
    const float* q = (const float*)d_in[0];
    const float* k = (const float*)d_in[1];
    const float* v = (const float*)d_in[2];
    const float* g = (const float*)d_in[3];
    float* out = (float*)d_out;

    float* SegKV = (float*)d_ws;                        // [1024][32][32] f32 (4.2 MB)
    float* SegLT = SegKV + (long)NBH * NSEG * D * D;    // [1024][32]      (128 KB)

    dim3 blk(256);
    kA_segsum<<<dim3(NBH * NSEG), blk, 0, stream>>>(k, v, g, SegKV, SegLT);
    kB_out<<<dim3(NBH * NSEG), blk, 0, stream>>>(q, k, v, g, SegKV, SegLT, out);
}

// Round 18
// 62.121 us; speedup vs baseline: 4.8734x; 1.0459x over previous
//
#include <hip/hip_runtime.h>

namespace {

constexpr int B = 4, S = 4096, H = 16, D = 32;
constexpr int L = 32;             // chunk length
constexpr int NC = S / L;         // 128 chunks per sequence
constexpr int NBH = B * H;        // 64
constexpr int RS = H * D;         // 512 floats between consecutive time steps
constexpr int NSEG = 16;          // segments per (b,h)
constexpr int SEGC = NC / NSEG;   // 8 chunks per segment
constexpr float GEPS = 1.52587890625e-05f;  // 2^-16 per-step decay clamp

// Lore (rounds 6-17, measured):
//  - launch_bounds(256,w) caps VGPR ~256/w; cap < live set => GB-scale spill.
//  - Scalar j-loops over LDS tiles are LDS-instruction bound -> MFMA.
//  - COLD scalar column loads (stride RS) are latency death (r13); row float4
//    for cold data; column loads OK when L3-warm (r12 k3).
//  - KVc state-update MFMA needs TOTAL-scaled W (x 2^{es4[3]-es4[sub]}), r16.
//  - r17: occupancy 2->4 blocks/CU did NOT speed kB -> bottleneck is the
//    intra-block serial relay + ~8 barriers/group, not residency.
//    This round: relay -> parallel compose (kv_s in LDS + closed-form
//    prefix scales); same-wave LDS needs no barrier -> 3 barriers/group.
//  - MFMA operand convention (HW-verified r12, absmax 0.5):
//    A-op: row = lane&31, k = 8*(lane>>5)+e (+16 for 2nd MFMA)
//    B-op: col = lane&31, same k
//    C/D : col = lane&31, row = (reg&3)+8*(reg>>2)+4*(lane>>5)

typedef __attribute__((ext_vector_type(8)))  short short8v;   // 8 bf16 = 4 VGPR
typedef __attribute__((ext_vector_type(16))) float f32x16;    // 16 f32 acc

__device__ __forceinline__ float flog2(float x) { return __builtin_amdgcn_logf(x); }
__device__ __forceinline__ float fexp2(float x) { return __builtin_amdgcn_exp2f(x); }
__device__ __forceinline__ unsigned f2bfu(float f) {          // fp32 -> bf16 (RNE)
    unsigned u = __float_as_uint(f);
    return (u + 0x7FFFu + ((u >> 16) & 1u)) >> 16;
}
__device__ __forceinline__ short f2bf(float f) { return (short)f2bfu(f); }
__device__ __forceinline__ float bf2f(short s) {              // bf16 -> fp32
    return __uint_as_float(((unsigned)(ushort)s) << 16);
}

// ---------------- Kernel A: segment summaries (unchanged, verified) -----------
__global__ __launch_bounds__(256)
void kA_segsum(const float* __restrict__ Kp, const float* __restrict__ Vp,
               const float* __restrict__ Gp, float* __restrict__ SegKV,
               float* __restrict__ SegLT)
{
    __shared__ __align__(16) float  k_s[L][36];
    __shared__ __align__(16) float  lg[L][36];
    __shared__ __align__(16) ushort w_s[L][40];
    __shared__ float sub[8][D];
    __shared__ float totr[D];
    __shared__ float S_lds[D][33];
    __shared__ float ltot[D];

    const int blk = blockIdx.x;              // bh*NSEG + seg
    const int bh = blk / NSEG, seg = blk % NSEG;
    const int b = bh >> 4, h = bh & (H - 1);

    const int tid = threadIdx.x;
    const int i = tid >> 3;
    const int u = (tid & 7) * 4;
    const int m = tid & 31, t = tid >> 5;
    const int r0 = t * 4;

    #pragma unroll
    for (int z = 0; z < 4; ++z) S_lds[i][u + z] = 0.f;
    if (tid < D) ltot[tid] = 0.f;

    for (int cc = 0; cc < SEGC; ++cc) {
        const int c = seg * SEGC + cc;
        const long base = ((long)b * S + (long)c * L) * RS + h * D;
        const long roff = base + (long)i * RS + u;
        float4 k4 = *(const float4*)(Kp + roff);
        float4 v4 = *(const float4*)(Vp + roff);
        float4 g4 = *(const float4*)(Gp + roff);
        __syncthreads();
        *(float4*)&k_s[i][u] = k4;
        float4 lv;
        lv.x = flog2(fmaxf(g4.x, GEPS));
        lv.y = flog2(fmaxf(g4.y, GEPS));
        lv.z = flog2(fmaxf(g4.z, GEPS));
        lv.w = flog2(fmaxf(g4.w, GEPS));
        *(float4*)&lg[i][u] = lv;
        __syncthreads();                     // b1

        float c0 = lg[r0 + 0][m];
        float c1 = c0 + lg[r0 + 1][m];
        float c2 = c1 + lg[r0 + 2][m];
        float c3 = c2 + lg[r0 + 3][m];
        sub[t][m] = c3;
        __syncthreads();                     // b2

        {
            float sb[8];
            float total = 0.f;
            #pragma unroll
            for (int tt = 0; tt < 8; ++tt) { sb[tt] = sub[tt][m]; total += sb[tt]; }
            float base_l = 0.f;
            #pragma unroll
            for (int tt = 0; tt < 8; ++tt) { if (tt < t) base_l += sb[tt]; }
            lg[r0 + 0][m] = base_l + c0;
            lg[r0 + 1][m] = base_l + c1;
            lg[r0 + 2][m] = base_l + c2;
            lg[r0 + 3][m] = base_l + c3;
            if (t == 0) { totr[m] = total; ltot[m] += total; }
        }
        __syncthreads();                     // b3

        {
            float4 l4 = *(float4*)&lg[i][u];
            float4 t4 = *(float4*)&totr[u];
            unsigned p0 = f2bfu(v4.x * fexp2(t4.x - l4.x))
                        | (f2bfu(v4.y * fexp2(t4.y - l4.y)) << 16);
            unsigned p1 = f2bfu(v4.z * fexp2(t4.z - l4.z))
                        | (f2bfu(v4.w * fexp2(t4.w - l4.w)) << 16);
            uint2 pp; pp.x = p0; pp.y = p1;
            *(uint2*)&w_s[i][u] = pp;
        }
        __syncthreads();                     // b4

        if (tid < 64) {
            const int half = tid >> 5;
            const int mm = tid & 31;
            short8v ka0, ka1, wf0, wf1;
            #pragma unroll
            for (int e = 0; e < 8; ++e) {
                ka0[e] = f2bf(k_s[8 * half + e][mm]);
                ka1[e] = f2bf(k_s[16 + 8 * half + e][mm]);
                wf0[e] = (short)w_s[8 * half + e][mm];
                wf1[e] = (short)w_s[16 + 8 * half + e][mm];
            }
            f32x16 acc;
            #pragma unroll
            for (int e = 0; e < 16; ++e) acc[e] = 0.f;
            acc = __builtin_amdgcn_mfma_f32_32x32x16_bf16(ka0, wf0, acc, 0, 0, 0);
            acc = __builtin_amdgcn_mfma_f32_32x32x16_bf16(ka1, wf1, acc, 0, 0, 0);
            const float gs = fexp2(totr[mm]);
            #pragma unroll
            for (int reg = 0; reg < 16; ++reg) {
                const int r = (reg & 3) + 8 * (reg >> 2) + 4 * half;
                S_lds[r][mm] = gs * S_lds[r][mm] + acc[reg];
            }
        }
    }
    __syncthreads();

    {
        float4 sv;
        sv.x = S_lds[i][u + 0]; sv.y = S_lds[i][u + 1];
        sv.z = S_lds[i][u + 2]; sv.w = S_lds[i][u + 3];
        *(float4*)(SegKV + (long)blk * (D * D) + i * D + u) = sv;
    }
    if (tid < D) SegLT[blk * D + tid] = ltot[tid];
}

// ---------------- Kernel B: compose start + outputs (relay-free) -------------
// One block per (bh, seg); 2 groups x 4 chunks (wave per chunk).
// Per group: phase1 (no barrier): loads, shfl scan, W/a_s/kv_s/totc;
// B_a; parallel compose of per-wave S0 from S_lds+kv_s+totc; QS0+P+store;
// B_b; parallel 5-term state update; B_c.
__global__ __launch_bounds__(256)
void kB_out(const float* __restrict__ Qp, const float* __restrict__ Kp,
            const float* __restrict__ Vp, const float* __restrict__ Gp,
            const float* __restrict__ SegKV, const float* __restrict__ SegLT,
            float* __restrict__ Op)
{
    __shared__ __align__(16) ushort w_s[4][L][36];   // W bf16 (scalar reads)
    __shared__ union AU {                            // lt8 dead before a_s live
        ushort a_s[4][L][40];                        // b128 row reads (80B rows)
        float  lt8[NSEG][D];
    } au;
    __shared__ float kv_s[4][L][32];                 // chunk KV, C-layout, f32
    __shared__ float S_lds[D][32];                   // running state
    __shared__ float totc[4][D];                     // per-chunk gate totals

    const int blk = blockIdx.x;
    const int bh = blk / NSEG, seg = blk % NSEG;
    const int b = bh >> 4, h = bh & (H - 1);

    const int tid = threadIdx.x;
    const int wv = tid >> 6;
    const int lane = tid & 63;
    const int half = lane >> 5;
    const int m = lane & 31;

    // stage SegLT for this bh (NSEG*D = 512 floats)
    for (int z = tid; z < NSEG * D; z += 256)
        au.lt8[z >> 5][z & 31] = SegLT[bh * NSEG * D + z];
    __syncthreads();

    // compose segment-start state from prior segment summaries (log space)
    {
        const int d = tid >> 3;
        const int u4 = (tid & 7) * 4;
        float4 Sv = {0, 0, 0, 0};
        float r0 = 0.f, r1 = 0.f, r2 = 0.f, r3 = 0.f;
        for (int sp = seg - 1; sp >= 0; --sp) {
            float4 kv = *(const float4*)(SegKV + (long)(bh * NSEG + sp) * (D * D)
                                         + d * D + u4);
            Sv.x += kv.x * fexp2(r0); Sv.y += kv.y * fexp2(r1);
            Sv.z += kv.z * fexp2(r2); Sv.w += kv.w * fexp2(r3);
            r0 += au.lt8[sp][u4 + 0]; r1 += au.lt8[sp][u4 + 1];
            r2 += au.lt8[sp][u4 + 2]; r3 += au.lt8[sp][u4 + 3];
        }
        S_lds[d][u4 + 0] = Sv.x; S_lds[d][u4 + 1] = Sv.y;
        S_lds[d][u4 + 2] = Sv.z; S_lds[d][u4 + 3] = Sv.w;
    }
    __syncthreads();    // lt8 dead; S_lds ready

    for (int grp = 0; grp < SEGC / 4; ++grp) {
        const int c = seg * SEGC + grp * 4 + wv;
        const long base = ((long)b * S + (long)c * L) * RS + h * D;

        // ======== phase 1: no block barriers (same-wave LDS only) ========
        const float* qrow = Qp + base + (long)m * RS + 8 * half;
        const float* krow = Kp + base + (long)m * RS + 8 * half;
        float4 qv0 = *(const float4*)(qrow);
        float4 qv1 = *(const float4*)(qrow + 4);
        float4 qv2 = *(const float4*)(qrow + 16);
        float4 qv3 = *(const float4*)(qrow + 20);
        float4 kv0 = *(const float4*)(krow);
        float4 kv1 = *(const float4*)(krow + 4);
        float4 kv2 = *(const float4*)(krow + 16);
        float4 kv3 = *(const float4*)(krow + 20);
        short8v qa0, qa1, kb0, kb1;
        {
            float qf[16] = {qv0.x,qv0.y,qv0.z,qv0.w, qv1.x,qv1.y,qv1.z,qv1.w,
                            qv2.x,qv2.y,qv2.z,qv2.w, qv3.x,qv3.y,qv3.z,qv3.w};
            float kf[16] = {kv0.x,kv0.y,kv0.z,kv0.w, kv1.x,kv1.y,kv1.z,kv1.w,
                            kv2.x,kv2.y,kv2.z,kv2.w, kv3.x,kv3.y,kv3.z,kv3.w};
            #pragma unroll
            for (int e = 0; e < 8; ++e) {
                qa0[e] = f2bf(qf[e]);     qa1[e] = f2bf(qf[8 + e]);
                kb0[e] = f2bf(kf[e]);     kb1[e] = f2bf(kf[8 + e]);
            }
        }

        // per-lane register cumsum of own half-column; cross-half via shfl
        float cum[16];
        {
            const float* gcol = Gp + base + (long)(half * 16) * RS + m;
            float run = 0.f;
            #pragma unroll
            for (int t = 0; t < 16; ++t) {
                run += flog2(fmaxf(gcol[(long)t * RS], GEPS));
                cum[t] = run;
            }
        }
        {
            const float oth = __shfl_xor(cum[15], 32);
            if (half) {
                #pragma unroll
                for (int t = 0; t < 16; ++t) cum[t] += oth;
            }
        }
        // es4 (sub-block end l) via one exchange
        const float c7 = cum[7], c15 = cum[15];
        const float o7 = __shfl_xor(c7, 32), o15 = __shfl_xor(c15, 32);
        float es4[4];
        es4[0] = half ? o7  : c7;
        es4[1] = half ? o15 : c15;
        es4[2] = half ? c7  : o7;
        es4[3] = half ? c15 : o15;
        if (half) totc[wv][m] = cum[15];     // chunk total per col

        // li at C-rows via 8 paired exchanges
        float li[16];
        #pragma unroll
        for (int j = 0; j < 8; ++j) {
            const int tl = (j & 3) + 8 * (j >> 2);     // 0..3, 8..11
            const float send = half ? cum[tl] : cum[tl + 4];
            const float recv = __shfl_xor(send, 32);
            li[j]     = half ? recv        : cum[tl];
            li[j + 8] = half ? cum[tl + 4] : recv;
        }

        // W = v * 2^{e_s(own row) - l}  (own rows; same-wave LDS)
        {
            const float* vcol = Vp + base + (long)(half * 16) * RS + m;
            #pragma unroll
            for (int t = 0; t < 16; ++t) {
                const float e = (t < 8) ? c7 : c15;
                const float w = vcol[(long)t * RS] * fexp2(e - cum[t]);
                w_s[wv][half * 16 + t][m] = (ushort)f2bf(w);
            }
        }

        // Gram A = Q.K^T -> masked bf16 a_s (same-wave)
        f32x16 acc;
        #pragma unroll
        for (int e = 0; e < 16; ++e) acc[e] = 0.f;
        acc = __builtin_amdgcn_mfma_f32_32x32x16_bf16(qa0, kb0, acc, 0, 0, 0);
        acc = __builtin_amdgcn_mfma_f32_32x32x16_bf16(qa1, kb1, acc, 0, 0, 0);
        #pragma unroll
        for (int reg = 0; reg < 16; ++reg) {
            const int irow = (reg & 3) + 8 * (reg >> 2) + 4 * half;
            const float av = (m <= irow) ? acc[reg] : 0.f;
            au.a_s[wv][irow][m] = (ushort)f2bf(av);
        }

        // W B-frags (sub-block-scaled, for P)  [same-wave LDS read]
        short8v wfk0, wfk1;
        #pragma unroll
        for (int e = 0; e < 8; ++e) {
            wfk0[e] = (short)w_s[wv][8 * half + e][m];
            wfk1[e] = (short)w_s[wv][16 + 8 * half + e][m];
        }
        // TOTAL-scaled W for KVc (r16 fix)
        const float fac0 = fexp2(es4[3] - es4[half]);
        const float fac1 = fexp2(es4[3] - es4[2 + half]);
        short8v wkv0, wkv1;
        #pragma unroll
        for (int e = 0; e < 8; ++e) {
            wkv0[e] = f2bf(bf2f(wfk0[e]) * fac0);
            wkv1[e] = f2bf(bf2f(wfk1[e]) * fac1);
        }
        // KVc = K^T . W_total  -> kv_s (f32, C-layout)
        {
            f32x16 kvacc;
            #pragma unroll
            for (int e = 0; e < 16; ++e) kvacc[e] = 0.f;
            const float* kcol = Kp + base + m;
            short8v kta0, kta1;
            #pragma unroll
            for (int e = 0; e < 8; ++e) {
                kta0[e] = f2bf(kcol[(long)(8 * half + e) * RS]);
                kta1[e] = f2bf(kcol[(long)(16 + 8 * half + e) * RS]);
            }
            kvacc = __builtin_amdgcn_mfma_f32_32x32x16_bf16(kta0, wkv0, kvacc, 0, 0, 0);
            kvacc = __builtin_amdgcn_mfma_f32_32x32x16_bf16(kta1, wkv1, kvacc, 0, 0, 0);
            #pragma unroll
            for (int reg = 0; reg < 16; ++reg) {
                const int r = (reg & 3) + 8 * (reg >> 2) + 4 * half;
                kv_s[wv][r][m] = kvacc[reg];
            }
        }

        __syncthreads();                       // B_a: kv_s, totc visible

        // ======== phase 2: parallel compose + outputs ========
        // prefix sums of chunk totals at this lane's col
        const float T0 = totc[0][m], T1 = totc[1][m],
                    T2 = totc[2][m], T3 = totc[3][m];
        const float PS1 = T0, PS2 = T0 + T1, PS3 = T0 + T1 + T2;
        const float Pw = (wv == 0) ? 0.f : (wv == 1) ? PS1
                       : (wv == 2) ? PS2 : PS3;
        const float cpre = fexp2(Pw);

        float sfA[8], sfB[8];
        #pragma unroll
        for (int e = 0; e < 8; ++e) {
            sfA[e] = cpre * S_lds[8 * half + e][m];
            sfB[e] = cpre * S_lds[16 + 8 * half + e][m];
        }
        #pragma unroll
        for (int s = 0; s < 3; ++s) {
            if (s < wv) {                       // wave-uniform
                const float PSs = (s == 0) ? PS1 : (s == 1) ? PS2 : PS3;
                const float cs = fexp2(Pw - PSs);
                #pragma unroll
                for (int e = 0; e < 8; ++e) {
                    sfA[e] += cs * kv_s[s][8 * half + e][m];
                    sfB[e] += cs * kv_s[s][16 + 8 * half + e][m];
                }
            }
        }
        short8v sf0, sf1;
        #pragma unroll
        for (int e = 0; e < 8; ++e) {
            sf0[e] = f2bf(sfA[e]);
            sf1[e] = f2bf(sfB[e]);
        }

        // QS0 + epilogue
        f32x16 sacc;
        #pragma unroll
        for (int e = 0; e < 16; ++e) sacc[e] = 0.f;
        sacc = __builtin_amdgcn_mfma_f32_32x32x16_bf16(qa0, sf0, sacc, 0, 0, 0);
        sacc = __builtin_amdgcn_mfma_f32_32x32x16_bf16(qa1, sf1, sacc, 0, 0, 0);
        f32x16 out;
        #pragma unroll
        for (int reg = 0; reg < 16; ++reg) out[reg] = fexp2(li[reg]) * sacc[reg];

        #pragma unroll
        for (int ks = 0; ks < 2; ++ks) {
            const short8v af = *(const short8v*)&au.a_s[wv][m][16 * ks + 8 * half];
            const short8v wf = ks ? wfk1 : wfk0;
            #pragma unroll
            for (int par = 0; par < 2; ++par) {
                const int s = 2 * ks + par;
                short8v am;
                #pragma unroll
                for (int e = 0; e < 8; ++e) am[e] = (half == par) ? af[e] : (short)0;
                f32x16 p;
                #pragma unroll
                for (int e = 0; e < 16; ++e) p[e] = 0.f;
                p = __builtin_amdgcn_mfma_f32_32x32x16_bf16(am, wf, p, 0, 0, 0);
                #pragma unroll
                for (int reg = 0; reg < 16; ++reg)
                    out[reg] += fexp2(fminf(li[reg] - es4[s], 120.f)) * p[reg];
            }
        }
        #pragma unroll
        for (int reg = 0; reg < 16; ++reg) {
            const int irow = (reg & 3) + 8 * (reg >> 2) + 4 * half;
            Op[base + (long)irow * RS + m] = out[reg];
        }

        // ======== state update for next group ========
        if (grp + 1 < SEGC / 4) {
            __syncthreads();                   // B_b: compose reads done
            {
                const int mu = tid & 31, tg = tid >> 5;
                const float U0 = totc[0][mu], U1 = totc[1][mu],
                            U2 = totc[2][mu], U3 = totc[3][mu];
                const float Q1 = U1 + U2 + U3, Q2 = U2 + U3;
                const float d0 = fexp2(Q1), d1 = fexp2(Q2), d2 = fexp2(U3);
                const float dall = fexp2(U0 + Q1);
                #pragma unroll
                for (int r = 0; r < 4; ++r) {
                    const int d = tg * 4 + r;
                    S_lds[d][mu] = dall * S_lds[d][mu]
                                 + d0 * kv_s[0][d][mu] + d1 * kv_s[1][d][mu]
                                 + d2 * kv_s[2][d][mu] + kv_s[3][d][mu];
                }
            }
            __syncthreads();                   // B_c: update done
        }
    }
}

} // namespace

extern "C" void kernel_launch(void* const* d_in, const int* in_sizes, int n_in,
                              void* d_out, int out_size, void* d_ws, size_t ws_size,
                              hipStream_t stream)
{
    const float* q = (const float*)d_in[0];
    const float* k = (const float*)d_in[1];
    const float* v = (const float*)d_in[2];
    const float* g = (const float*)d_in[3];
    float* out = (float*)d_out;

    float* SegKV = (float*)d_ws;                        // [1024][32][32] f32 (4.2 MB)
    float* SegLT = SegKV + (long)NBH * NSEG * D * D;    // [1024][32]      (128 KB)

    dim3 blk(256);
    kA_segsum<<<dim3(NBH * NSEG), blk, 0, stream>>>(k, v, g, SegKV, SegLT);
    kB_out<<<dim3(NBH * NSEG), blk, 0, stream>>>(q, k, v, g, SegKV, SegLT, out);
}